// Round 16
// baseline (110.425 us; speedup 1.0000x reference)
//
#include <hip/hip_runtime.h>
#include <hip/hip_bf16.h>
#include <math.h>

// Problem constants
#define B_SZ 8
#define N_SZ 1024
#define D_IN 3072
#define H_SZ 128
#define NH 4
#define DH 32
#define TWO_H 256
#define LN_EPS 1e-5f
#define CAP 128    // max neighbors per row (binomial max deg ~80 << 128)

typedef __attribute__((ext_vector_type(8))) short bf16x8;
typedef __attribute__((ext_vector_type(8))) unsigned short u16x8;
typedef __attribute__((ext_vector_type(4))) float f32x4;
typedef __attribute__((ext_vector_type(4))) unsigned int u32x4;

// round-to-nearest-even fp32 -> bf16 bits
__device__ inline unsigned short f2bf(float f) {
    unsigned int u = __builtin_bit_cast(unsigned int, f);
    u += 0x7fffu + ((u >> 16) & 1u);
    return (unsigned short)(u >> 16);
}

// ---------------------------------------------------------------------------
// 0) Convert all GEMM weights to bf16 ONCE (W-row-major [j][k] kept: that IS
//    the MFMA B-fragment-friendly layout, B[k][col] = W[col][k] contiguous).
//    wb16 layout (ushorts): [0] wcat1[128][384] = [Wfu1[j][0:256] | Wsk1[j]]
//    [49152] wcat2 ; [98304] Wf1 ; [114688] Wr1 ; [131072] Wf2 ; [147456] Wr2
// ---------------------------------------------------------------------------
__global__ void cvtw_kernel(const float* __restrict__ Wfu1, const float* __restrict__ Wsk1,
                            const float* __restrict__ Wfu2, const float* __restrict__ Wsk2,
                            const float* __restrict__ Wf1, const float* __restrict__ Wr1,
                            const float* __restrict__ Wf2, const float* __restrict__ Wr2,
                            unsigned short* __restrict__ wb) {
    const int j = blockIdx.x;   // 0..127
    const int t = threadIdx.x;  // 0..255
    wb[j * 384 + t] = f2bf(Wfu1[j * 256 + t]);
    wb[49152 + j * 384 + t] = f2bf(Wfu2[j * 256 + t]);
    if (t < 128) {
        wb[j * 384 + 256 + t]         = f2bf(Wsk1[j * 128 + t]);
        wb[49152 + j * 384 + 256 + t] = f2bf(Wsk2[j * 128 + t]);
        wb[98304  + j * 128 + t] = f2bf(Wf1[j * 128 + t]);
        wb[114688 + j * 128 + t] = f2bf(Wr1[j * 128 + t]);
        wb[131072 + j * 128 + t] = f2bf(Wf2[j * 128 + t]);
        wb[147456 + j * 128 + t] = f2bf(Wr2[j * 128 + t]);
    }
}

// ---------------------------------------------------------------------------
// 1a) enc1: z[b][j] = b1[j] + dot(stim[b,:], W1[j,:])
// ---------------------------------------------------------------------------
__global__ void enc1_kernel(const float* __restrict__ stim,
                            const float* __restrict__ W1, const float* __restrict__ b1,
                            float* __restrict__ z) {
    const int j = blockIdx.x;     // 0..255
    const int tid = threadIdx.x;  // 0..255
    const float4* w4 = (const float4*)(W1 + (size_t)j * D_IN);
    const float4* s4 = (const float4*)stim;

    float acc[B_SZ];
    #pragma unroll
    for (int b = 0; b < B_SZ; ++b) acc[b] = 0.0f;

    #pragma unroll
    for (int i = 0; i < D_IN / 4 / 256; ++i) {  // 3 iters
        const int k4 = tid + i * 256;
        const float4 w = w4[k4];
        #pragma unroll
        for (int b = 0; b < B_SZ; ++b) {
            const float4 s = s4[b * (D_IN / 4) + k4];
            acc[b] += s.x * w.x + s.y * w.y + s.z * w.z + s.w * w.w;
        }
    }

    #pragma unroll
    for (int b = 0; b < B_SZ; ++b) {
        float v = acc[b];
        v += __shfl_xor(v, 1);  v += __shfl_xor(v, 2);  v += __shfl_xor(v, 4);
        v += __shfl_xor(v, 8);  v += __shfl_xor(v, 16); v += __shfl_xor(v, 32);
        acc[b] = v;
    }
    __shared__ float red[4][B_SZ];
    const int wave = tid >> 6, lane = tid & 63;
    if (lane == 0) {
        #pragma unroll
        for (int b = 0; b < B_SZ; ++b) red[wave][b] = acc[b];
    }
    __syncthreads();
    if (tid < B_SZ) {
        float v = red[0][tid] + red[1][tid] + red[2][tid] + red[3][tid];
        z[tid * TWO_H + j] = v + b1[j];
    }
}

// ---------------------------------------------------------------------------
// 1b) enc2: LayerNorm + exact GELU over z rows. grid = 8 blocks x 256 threads.
// ---------------------------------------------------------------------------
__global__ void enc2_kernel(const float* __restrict__ z,
                            const float* __restrict__ lng, const float* __restrict__ lnb,
                            float* __restrict__ zg) {
    __shared__ float red[TWO_H];
    const int b = blockIdx.x;
    const int tid = threadIdx.x;

    float zi = z[b * TWO_H + tid];
    red[tid] = zi; __syncthreads();
    for (int s = 128; s > 0; s >>= 1) { if (tid < s) red[tid] += red[tid + s]; __syncthreads(); }
    float mu = red[0] * (1.0f / TWO_H);
    __syncthreads();
    float dz = zi - mu;
    red[tid] = dz * dz; __syncthreads();
    for (int s = 128; s > 0; s >>= 1) { if (tid < s) red[tid] += red[tid + s]; __syncthreads(); }
    float var = red[0] * (1.0f / TWO_H);

    float zn = dz * (1.0f / sqrtf(var + LN_EPS)) * lng[tid] + lnb[tid];
    zg[b * TWO_H + tid] = 0.5f * zn * (1.0f + erff(zn * 0.70710678118654752f));
}

// ---------------------------------------------------------------------------
// 1c) enc3: g[b][j] = b2[j] + dot(zg[b,:], W2[j,:])
// ---------------------------------------------------------------------------
__global__ void enc3_kernel(const float* __restrict__ zg,
                            const float* __restrict__ W2, const float* __restrict__ b2,
                            float* __restrict__ g) {
    const int j = blockIdx.x;     // 0..127
    const int tid = threadIdx.x;  // 0..255
    const float w = W2[(size_t)j * TWO_H + tid];

    float acc[B_SZ];
    #pragma unroll
    for (int b = 0; b < B_SZ; ++b) acc[b] = zg[b * TWO_H + tid] * w;

    #pragma unroll
    for (int b = 0; b < B_SZ; ++b) {
        float v = acc[b];
        v += __shfl_xor(v, 1);  v += __shfl_xor(v, 2);  v += __shfl_xor(v, 4);
        v += __shfl_xor(v, 8);  v += __shfl_xor(v, 16); v += __shfl_xor(v, 32);
        acc[b] = v;
    }
    __shared__ float red[4][B_SZ];
    const int wave = tid >> 6, lane = tid & 63;
    if (lane == 0) {
        #pragma unroll
        for (int b = 0; b < B_SZ; ++b) red[wave][b] = acc[b];
    }
    __syncthreads();
    if (tid < B_SZ)
        g[tid * H_SZ + j] = red[0][tid] + red[1][tid] + red[2][tid] + red[3][tid] + b2[j];
}

// ---------------------------------------------------------------------------
// 2) Build both neighbor lists. One WAVE per row; ballot-compaction preserves
//    ascending order. grid = (N_SZ, 2) x 64 threads. deg capped at CAP=128.
// ---------------------------------------------------------------------------
__global__ void csr_kernel(const float* __restrict__ m0, const float* __restrict__ m1,
                           int* __restrict__ i0, int* __restrict__ i1,
                           int* __restrict__ d0, int* __restrict__ d1) {
    const float* mask = blockIdx.y ? m1 : m0;
    int* idx = blockIdx.y ? i1 : i0;
    int* deg = blockIdx.y ? d1 : d0;

    const int row = blockIdx.x;
    const int lane = threadIdx.x;  // 0..63
    const float* mrow = mask + (size_t)row * N_SZ;
    int* irow = idx + (size_t)row * CAP;

    int base = 0;
    #pragma unroll 4
    for (int t = 0; t < N_SZ / 64; ++t) {
        int c = t * 64 + lane;
        bool edge = (mrow[c] == 0.0f);
        unsigned long long ball = __ballot(edge);
        unsigned long long below = ball & ((1ull << lane) - 1ull);
        if (edge) {
            int p = base + __popcll(below);
            if (p < CAP) irow[p] = c;
        }
        base += __popcll(ball);
    }
    if (lane == 0) deg[row] = (base < CAP) ? base : CAP;
}

// ---------------------------------------------------------------------------
// 3) x[b,n,c] = g[b,c] + voxel_emb[n,c]
// ---------------------------------------------------------------------------
__global__ void addemb_kernel(const float* __restrict__ g, const float* __restrict__ emb,
                              float* __restrict__ x) {
    int idx = blockIdx.x * blockDim.x + threadIdx.x;
    int c = idx & 127;
    int n = (idx >> 7) & 1023;
    int b = idx >> 17;
    x[idx] = g[b * H_SZ + c] + emb[n * H_SZ + c];
}

// ---------------------------------------------------------------------------
// 4) MFMA GEMM: out[row][j] = sum_seg sum_k a_seg[row][k] * W[j][seg*128+k]
//    (+ optional biases). bf16 inputs (RNE-converted), fp32 accumulation via
//    v_mfma_f32_16x16x32_bf16. OB16: write bf16 output (for attn consumers).
//    Block = 32 rows x 64 cols, 256 thr = 4 waves (2M x 2N). K staged in
//    128-chunks: As[32][128] + Bs[64][128] bf16, XOR-swizzled 16B granules.
// ---------------------------------------------------------------------------
template<int NSEG, bool OB16>
__global__ __launch_bounds__(256) void gemm_mfma(
        const float* __restrict__ a0, const float* __restrict__ a1,
        const float* __restrict__ a2,
        const unsigned short* __restrict__ wba, const unsigned short* __restrict__ wbb,
        const float* __restrict__ bias1, const float* __restrict__ bias2,
        float* __restrict__ outa, float* __restrict__ outb) {
    const unsigned short* wb = blockIdx.y ? wbb : wba;
    float* out = blockIdx.y ? outb : outa;
    const int KW = NSEG * 128;   // weight row stride (ushorts)

    __shared__ __align__(16) short As[32 * 128];
    __shared__ __align__(16) short Bs[64 * 128];

    const int bid = blockIdx.x;
    const int ct = bid & 1, rt = bid >> 1;
    const int row0 = rt * 32, col0 = ct * 64;
    const int tid = threadIdx.x;
    const int lane = tid & 63, w = tid >> 6;
    const int wm = w >> 1, wn = w & 1;
    const int lrow = lane & 15, lk = lane >> 4;

    f32x4 acc0 = {0.f, 0.f, 0.f, 0.f};
    f32x4 acc1 = {0.f, 0.f, 0.f, 0.f};

    for (int seg = 0; seg < NSEG; ++seg) {
        const float* src = (seg == 0) ? a0 : ((seg == 1) ? a1 : a2);
        if (seg) __syncthreads();
        // stage A: 32 rows x 128 k, fp32 -> bf16, swizzled 16B granules
        for (int gi = tid; gi < 512; gi += 256) {
            const int r = gi >> 4, kq = gi & 15;
            const float4* sp = (const float4*)(src + (size_t)(row0 + r) * H_SZ) + kq * 2;
            const float4 v0 = sp[0], v1 = sp[1];
            u16x8 t;
            t[0] = f2bf(v0.x); t[1] = f2bf(v0.y); t[2] = f2bf(v0.z); t[3] = f2bf(v0.w);
            t[4] = f2bf(v1.x); t[5] = f2bf(v1.y); t[6] = f2bf(v1.z); t[7] = f2bf(v1.w);
            *(u16x8*)&As[r * 128 + ((kq * 8) ^ ((r & 7) << 3))] = t;
        }
        // stage B: 64 cols x 128 k (already bf16, contiguous 16B per granule)
        for (int gi = tid; gi < 1024; gi += 256) {
            const int c = gi >> 4, kq = gi & 15;
            const float4 v = *(const float4*)(wb + (size_t)(col0 + c) * KW + seg * 128 + kq * 8);
            *(float4*)&Bs[c * 128 + ((kq * 8) ^ ((c & 7) << 3))] = v;
        }
        __syncthreads();

        #pragma unroll
        for (int ks = 0; ks < 4; ++ks) {
            const int kof = ks * 32 + lk * 8;
            const int r = wm * 16 + lrow;
            const bf16x8 a = *(const bf16x8*)&As[r * 128 + (kof ^ ((r & 7) << 3))];
            const int c0 = wn * 32 + lrow;
            const bf16x8 b0 = *(const bf16x8*)&Bs[c0 * 128 + (kof ^ ((c0 & 7) << 3))];
            const int c1 = c0 + 16;
            const bf16x8 b1 = *(const bf16x8*)&Bs[c1 * 128 + (kof ^ ((c1 & 7) << 3))];
            acc0 = __builtin_amdgcn_mfma_f32_16x16x32_bf16(a, b0, acc0, 0, 0, 0);
            acc1 = __builtin_amdgcn_mfma_f32_16x16x32_bf16(a, b1, acc1, 0, 0, 0);
        }
    }

    // epilogue: D lane l reg r -> row=(l>>4)*4+r, col=l&15
    const int rb = row0 + wm * 16 + lk * 4;
    #pragma unroll
    for (int fc = 0; fc < 2; ++fc) {
        const int c = col0 + wn * 32 + fc * 16 + lrow;
        const float bias = (bias1 ? bias1[c] : 0.0f) + (bias2 ? bias2[c] : 0.0f);
        const f32x4 a = fc ? acc1 : acc0;
        #pragma unroll
        for (int rr = 0; rr < 4; ++rr) {
            if constexpr (OB16) {
                ((unsigned short*)out)[(size_t)(rb + rr) * H_SZ + c] = f2bf(a[rr] + bias);
            } else {
                out[(size_t)(rb + rr) * H_SZ + c] = a[rr] + bias;
            }
        }
    }
}

// ---------------------------------------------------------------------------
// 5) Sparse masked attention + ELU, bf16 coalesced neighbor-parallel.
//    grid = (2048, 2) x 256 threads; 4 row-waves/block; b = bid&7 (XCD pin).
//    Wh is bf16 (proj writes it): row = 256B -> one load instruction covers
//    FOUR complete kv rows (vs 2 at fp32): half the bytes, half the line
//    requests. lane = (e4 = lane>>4 edge slot, c = lane&15 chunk of 8 ch).
//    Head h = lanes 4h..4h+3: dot = 8 FMA + xor1 + xor2. Indices preloaded
//    to registers, readlane-extracted. Max-free softmax (scores << 1) exact.
// ---------------------------------------------------------------------------
__global__ __launch_bounds__(256) void attn_kernel(
        const unsigned short* __restrict__ Wha, const unsigned short* __restrict__ Whb,
        const int* __restrict__ ia, const int* __restrict__ ib,
        const int* __restrict__ da, const int* __restrict__ db,
        float* __restrict__ oa, float* __restrict__ ob) {
    const unsigned short* Wh = blockIdx.y ? Whb : Wha;
    const int* idx = blockIdx.y ? ib : ia;
    const int* deg = blockIdx.y ? db : da;
    float* out = blockIdx.y ? ob : oa;

    const int bid = blockIdx.x;
    const int b = bid & 7;                                  // batch -> XCD
    const int i = ((bid >> 3) << 2) | (threadIdx.x >> 6);   // row
    const int bi = b * N_SZ + i;
    const int lane = threadIdx.x & 63;
    const int c = lane & 15;      // 16B chunk (8 channels) within a 256B row
    const int e4 = lane >> 4;     // which of the 4 edges per instruction

    // q chunk: 8 channels bf16 -> fp32, pre-scaled 1/sqrt(32)*log2(e)
    const u32x4 qb = *(const u32x4*)(Wh + (size_t)bi * H_SZ + c * 8);
    float qf[8];
    #pragma unroll
    for (int m = 0; m < 4; ++m) {
        qf[2 * m]     = __builtin_bit_cast(float, qb[m] << 16) * 0.25505654741110714f;
        qf[2 * m + 1] = __builtin_bit_cast(float, qb[m] & 0xffff0000u) * 0.25505654741110714f;
    }

    const int dg = deg[i];
    const int* row = idx + (size_t)i * CAP;
    int idxv0 = row[lane] & 1023;
    int idxv1 = (dg > 64) ? (row[64 + lane] & 1023) : 0;

    const unsigned short* kbase = Wh + (size_t)b * N_SZ * H_SZ;

    float acc[8];
    #pragma unroll
    for (int k = 0; k < 8; ++k) acc[k] = 0.0f;
    float l = 0.0f;

    const int nseg = (dg + 15) >> 4;
    for (int seg = 0; seg < nseg; ++seg) {
        const int srcv = (seg >= 4) ? idxv1 : idxv0;
        const int off16 = (seg & 3) << 4;
        // stage 16 edges: 4 instructions, each loading 4 full 256B rows
        u32x4 kv[4];
        #pragma unroll
        for (int t = 0; t < 4; ++t) {
            const int j0 = __builtin_amdgcn_readlane(srcv, off16 + 4 * t);
            const int j1 = __builtin_amdgcn_readlane(srcv, off16 + 4 * t + 1);
            const int j2 = __builtin_amdgcn_readlane(srcv, off16 + 4 * t + 2);
            const int j3 = __builtin_amdgcn_readlane(srcv, off16 + 4 * t + 3);
            const int jlo = (e4 & 1) ? j1 : j0;
            const int jhi = (e4 & 1) ? j3 : j2;
            const int j = (e4 & 2) ? jhi : jlo;
            kv[t] = *(const u32x4*)(kbase + (size_t)j * H_SZ + c * 8);
        }
        const int ebase = seg << 4;
        #pragma unroll
        for (int t = 0; t < 4; ++t) {
            float kf[8];
            #pragma unroll
            for (int m = 0; m < 4; ++m) {
                kf[2 * m]     = __builtin_bit_cast(float, kv[t][m] << 16);
                kf[2 * m + 1] = __builtin_bit_cast(float, kv[t][m] & 0xffff0000u);
            }
            float s = 0.0f;
            #pragma unroll
            for (int k = 0; k < 8; ++k) s += qf[k] * kf[k];
            s += __shfl_xor(s, 1);
            s += __shfl_xor(s, 2);      // full 32-ch head dot in all 4 lanes
            const bool valid = (ebase + 4 * t + e4) < dg;
            const float p = valid ? __builtin_amdgcn_exp2f(s) : 0.0f;
            l += p;
            #pragma unroll
            for (int k = 0; k < 8; ++k) acc[k] += p * kf[k];
        }
    }

    // combine the four edge-quarters
    l += __shfl_xor(l, 16);
    l += __shfl_xor(l, 32);
    #pragma unroll
    for (int k = 0; k < 8; ++k) {
        acc[k] += __shfl_xor(acc[k], 16);
        acc[k] += __shfl_xor(acc[k], 32);
    }

    if (e4 == 0) {
        const float inv = 1.0f / l;
        float o[8];
        #pragma unroll
        for (int k = 0; k < 8; ++k) {
            const float hp = acc[k] * inv;
            o[k] = (hp > 0.0f) ? hp
                 : (__builtin_amdgcn_exp2f(hp * 1.4426950408889634f) - 1.0f);
        }
        float4 v0 = {o[0], o[1], o[2], o[3]};
        float4 v1 = {o[4], o[5], o[6], o[7]};
        *(float4*)(out + (size_t)bi * H_SZ + c * 8) = v0;      // 16 lanes: 512B
        *(float4*)(out + (size_t)bi * H_SZ + c * 8 + 4) = v1;
    }
}

// ---------------------------------------------------------------------------
// 6) Readout: pred[row] = dot(x[row,:], W_ro) + b_ro. 64 threads/block.
// ---------------------------------------------------------------------------
__global__ void readout_kernel(const float* __restrict__ x, const float* __restrict__ Wro,
                               const float* __restrict__ bro, float* __restrict__ out) {
    const int row = blockIdx.x;
    const int lane = threadIdx.x;  // 0..63
    float s = x[(size_t)row * H_SZ + lane] * Wro[lane]
            + x[(size_t)row * H_SZ + 64 + lane] * Wro[64 + lane];
    #pragma unroll
    for (int m = 32; m >= 1; m >>= 1) s += __shfl_xor(s, m);
    if (lane == 0) out[row] = s + bro[0];
}

// ---------------------------------------------------------------------------
extern "C" void kernel_launch(void* const* d_in, const int* in_sizes, int n_in,
                              void* d_out, int out_size, void* d_ws, size_t ws_size,
                              hipStream_t stream) {
    const float* stim   = (const float*)d_in[0];
    const float* W_enc1 = (const float*)d_in[1];
    const float* b_enc1 = (const float*)d_in[2];
    const float* ln_g   = (const float*)d_in[3];
    const float* ln_b   = (const float*)d_in[4];
    const float* W_enc2 = (const float*)d_in[5];
    const float* b_enc2 = (const float*)d_in[6];
    const float* vox    = (const float*)d_in[7];
    const float* W_f1   = (const float*)d_in[8];
    const float* W_r1   = (const float*)d_in[9];
    const float* W_f2   = (const float*)d_in[10];
    const float* W_r2   = (const float*)d_in[11];
    const float* W_fu1  = (const float*)d_in[12];
    const float* b_fu1  = (const float*)d_in[13];
    const float* W_fu2  = (const float*)d_in[14];
    const float* b_fu2  = (const float*)d_in[15];
    const float* W_sk1  = (const float*)d_in[16];
    const float* b_sk1  = (const float*)d_in[17];
    const float* W_sk2  = (const float*)d_in[18];
    const float* b_sk2  = (const float*)d_in[19];
    const float* W_ro   = (const float*)d_in[20];
    const float* b_ro   = (const float*)d_in[21];
    const float* mask_f = (const float*)d_in[22];
    const float* mask_r = (const float*)d_in[23];

    float* pred = (float*)d_out;

    // workspace layout (floats)
    float* ws  = (float*)d_ws;
    float* z   = ws;                    // 8*256
    float* zg  = z + 2048;              // 8*256
    float* g   = zg + 2048;             // 8*128
    float* x   = g + 1024;              // 8*1024*128 fp32
    float* hf  = x + 1048576;
    float* hr  = hf + 1048576;
    float* x2  = hr + 1048576;
    unsigned short* Whf16 = (unsigned short*)(x2 + 1048576);  // 1048576 ushorts
    unsigned short* Whr16 = Whf16 + 1048576;
    int* idxf  = (int*)(Whr16 + 1048576);   // 1024*CAP
    int* idxr  = idxf + N_SZ * CAP;
    int* degf  = idxr + N_SZ * CAP;
    int* degr  = degf + N_SZ;
    unsigned short* wb16 = (unsigned short*)(degr + N_SZ);   // 163840 ushorts
    unsigned short* wcat1 = wb16;
    unsigned short* wcat2 = wb16 + 49152;
    unsigned short* wpf1  = wb16 + 98304;
    unsigned short* wpr1  = wb16 + 114688;
    unsigned short* wpf2  = wb16 + 131072;
    unsigned short* wpr2  = wb16 + 147456;

    const int BN = B_SZ * N_SZ;  // 8192

    // weight bf16 conversion (independent of everything else)
    cvtw_kernel<<<H_SZ, 256, 0, stream>>>(W_fu1, W_sk1, W_fu2, W_sk2,
                                          W_f1, W_r1, W_f2, W_r2, wb16);
    // encoder
    enc1_kernel<<<TWO_H, 256, 0, stream>>>(stim, W_enc1, b_enc1, z);
    enc2_kernel<<<B_SZ, 256, 0, stream>>>(z, ln_g, ln_b, zg);
    enc3_kernel<<<H_SZ, 256, 0, stream>>>(zg, W_enc2, b_enc2, g);
    // neighbor lists (both masks in one launch)
    csr_kernel<<<dim3(N_SZ, 2), 64, 0, stream>>>(mask_f, mask_r, idxf, idxr, degf, degr);
    // x = g + voxel_emb
    addemb_kernel<<<(BN * H_SZ) / 256, 256, 0, stream>>>(g, vox, x);

    // ---- GAT layer 1 ----
    gemm_mfma<1, true><<<dim3(BN / 32 * 2, 2), 256, 0, stream>>>(
        x, x, x, wpf1, wpr1, nullptr, nullptr, (float*)Whf16, (float*)Whr16);
    attn_kernel<<<dim3(BN / 4, 2), 256, 0, stream>>>(Whf16, Whr16, idxf, idxr, degf, degr,
                                                     hf, hr);
    gemm_mfma<3, false><<<dim3(BN / 32 * 2, 1), 256, 0, stream>>>(
        hf, hr, x, wcat1, wcat1, b_fu1, b_sk1, x2, x2);

    // ---- GAT layer 2 ----
    gemm_mfma<1, true><<<dim3(BN / 32 * 2, 2), 256, 0, stream>>>(
        x2, x2, x2, wpf2, wpr2, nullptr, nullptr, (float*)Whf16, (float*)Whr16);
    attn_kernel<<<dim3(BN / 4, 2), 256, 0, stream>>>(Whf16, Whr16, idxf, idxr, degf, degr,
                                                     hf, hr);
    gemm_mfma<3, false><<<dim3(BN / 32 * 2, 1), 256, 0, stream>>>(
        hf, hr, x2, wcat2, wcat2, b_fu2, b_sk2, x, x);

    // readout
    readout_kernel<<<BN, 64, 0, stream>>>(x, W_ro, b_ro, pred);
}

// Round 17
// 100.723 us; speedup vs baseline: 1.0963x; 1.0963x over previous
//
#include <hip/hip_runtime.h>
#include <hip/hip_bf16.h>
#include <math.h>

// Problem constants
#define B_SZ 8
#define N_SZ 1024
#define D_IN 3072
#define H_SZ 128
#define NH 4
#define DH 32
#define TWO_H 256
#define LN_EPS 1e-5f
#define CAP 128    // max neighbors per row (binomial max deg ~80 << 128)

typedef __attribute__((ext_vector_type(8))) short bf16x8;
typedef __attribute__((ext_vector_type(8))) unsigned short u16x8;
typedef __attribute__((ext_vector_type(4))) float f32x4;
typedef __attribute__((ext_vector_type(4))) unsigned int u32x4;

// round-to-nearest-even fp32 -> bf16 bits
__device__ inline unsigned short f2bf(float f) {
    unsigned int u = __builtin_bit_cast(unsigned int, f);
    u += 0x7fffu + ((u >> 16) & 1u);
    return (unsigned short)(u >> 16);
}

// ---------------------------------------------------------------------------
// 1) prep: three independent jobs in one launch (256 thr each):
//    blocks [0,128)    : cvtw  — bf16-convert all GEMM weights
//    blocks [128,640)  : csr   — neighbor lists, 4 row-waves/block
//    blocks [640,896)  : enc1  — z[b][j] = b1[j] + stim[b,:].W1[j,:]
// ---------------------------------------------------------------------------
__global__ __launch_bounds__(256) void prep_kernel(
        // cvtw
        const float* __restrict__ Wfu1, const float* __restrict__ Wsk1,
        const float* __restrict__ Wfu2, const float* __restrict__ Wsk2,
        const float* __restrict__ Wf1, const float* __restrict__ Wr1,
        const float* __restrict__ Wf2, const float* __restrict__ Wr2,
        unsigned short* __restrict__ wb,
        // csr
        const float* __restrict__ m0, const float* __restrict__ m1,
        int* __restrict__ i0, int* __restrict__ i1,
        int* __restrict__ d0, int* __restrict__ d1,
        // enc1
        const float* __restrict__ stim, const float* __restrict__ W1,
        const float* __restrict__ b1, float* __restrict__ z) {
    const int bid = blockIdx.x;
    const int tid = threadIdx.x;

    if (bid < 128) {
        // ------- cvtw -------
        const int j = bid;
        wb[j * 384 + tid] = f2bf(Wfu1[j * 256 + tid]);
        wb[49152 + j * 384 + tid] = f2bf(Wfu2[j * 256 + tid]);
        if (tid < 128) {
            wb[j * 384 + 256 + tid]         = f2bf(Wsk1[j * 128 + tid]);
            wb[49152 + j * 384 + 256 + tid] = f2bf(Wsk2[j * 128 + tid]);
            wb[98304  + j * 128 + tid] = f2bf(Wf1[j * 128 + tid]);
            wb[114688 + j * 128 + tid] = f2bf(Wr1[j * 128 + tid]);
            wb[131072 + j * 128 + tid] = f2bf(Wf2[j * 128 + tid]);
            wb[147456 + j * 128 + tid] = f2bf(Wr2[j * 128 + tid]);
        }
    } else if (bid < 640) {
        // ------- csr: one wave per row, ballot compaction -------
        const int bIdx = bid - 128;          // 0..511
        const int gsel = bIdx >> 8;          // graph
        const float* mask = gsel ? m1 : m0;
        int* idx = gsel ? i1 : i0;
        int* deg = gsel ? d1 : d0;
        const int row = (bIdx & 255) * 4 + (tid >> 6);
        const int lane = tid & 63;
        const float* mrow = mask + (size_t)row * N_SZ;
        int* irow = idx + (size_t)row * CAP;

        int base = 0;
        #pragma unroll 4
        for (int t = 0; t < N_SZ / 64; ++t) {
            int c = t * 64 + lane;
            bool edge = (mrow[c] == 0.0f);
            unsigned long long ball = __ballot(edge);
            unsigned long long below = ball & ((1ull << lane) - 1ull);
            if (edge) {
                int p = base + __popcll(below);
                if (p < CAP) irow[p] = c;
            }
            base += __popcll(ball);
        }
        if (lane == 0) deg[row] = (base < CAP) ? base : CAP;
    } else {
        // ------- enc1 -------
        const int j = bid - 640;      // 0..255
        const float4* w4 = (const float4*)(W1 + (size_t)j * D_IN);
        const float4* s4 = (const float4*)stim;

        float acc[B_SZ];
        #pragma unroll
        for (int b = 0; b < B_SZ; ++b) acc[b] = 0.0f;

        #pragma unroll
        for (int i = 0; i < D_IN / 4 / 256; ++i) {
            const int k4 = tid + i * 256;
            const float4 w = w4[k4];
            #pragma unroll
            for (int b = 0; b < B_SZ; ++b) {
                const float4 s = s4[b * (D_IN / 4) + k4];
                acc[b] += s.x * w.x + s.y * w.y + s.z * w.z + s.w * w.w;
            }
        }
        #pragma unroll
        for (int b = 0; b < B_SZ; ++b) {
            float v = acc[b];
            v += __shfl_xor(v, 1);  v += __shfl_xor(v, 2);  v += __shfl_xor(v, 4);
            v += __shfl_xor(v, 8);  v += __shfl_xor(v, 16); v += __shfl_xor(v, 32);
            acc[b] = v;
        }
        __shared__ float red[4][B_SZ];
        const int wave = tid >> 6, lane = tid & 63;
        if (lane == 0) {
            #pragma unroll
            for (int b = 0; b < B_SZ; ++b) red[wave][b] = acc[b];
        }
        __syncthreads();
        if (tid < B_SZ) {
            float v = red[0][tid] + red[1][tid] + red[2][tid] + red[3][tid];
            z[tid * TWO_H + j] = v + b1[j];
        }
    }
}

// ---------------------------------------------------------------------------
// 2) enc23: LayerNorm + exact GELU + enc3 in one kernel. grid = 8 x 256.
//    thread t: channel j = t&127, K-half = t>>7 (dot 128 each, LDS combine).
// ---------------------------------------------------------------------------
__global__ __launch_bounds__(256) void enc23_kernel(
        const float* __restrict__ z,
        const float* __restrict__ lng, const float* __restrict__ lnb,
        const float* __restrict__ W2, const float* __restrict__ b2,
        float* __restrict__ g) {
    __shared__ float red[TWO_H];
    __shared__ float zgs[TWO_H];
    __shared__ float gp[2][H_SZ];
    const int b = blockIdx.x;
    const int tid = threadIdx.x;

    float zi = z[b * TWO_H + tid];
    red[tid] = zi; __syncthreads();
    for (int s = 128; s > 0; s >>= 1) { if (tid < s) red[tid] += red[tid + s]; __syncthreads(); }
    float mu = red[0] * (1.0f / TWO_H);
    __syncthreads();
    float dz = zi - mu;
    red[tid] = dz * dz; __syncthreads();
    for (int s = 128; s > 0; s >>= 1) { if (tid < s) red[tid] += red[tid + s]; __syncthreads(); }
    float var = red[0] * (1.0f / TWO_H);

    float zn = dz * (1.0f / sqrtf(var + LN_EPS)) * lng[tid] + lnb[tid];
    zgs[tid] = 0.5f * zn * (1.0f + erff(zn * 0.70710678118654752f));
    __syncthreads();

    const int j = tid & 127, half = tid >> 7;
    const float* w2r = W2 + (size_t)j * TWO_H + half * 128;
    const float* zh = &zgs[half * 128];
    float s = 0.0f;
    #pragma unroll 4
    for (int k = 0; k < 128; ++k) s += zh[k] * w2r[k];
    gp[half][j] = s;
    __syncthreads();
    if (tid < H_SZ) g[b * H_SZ + tid] = gp[0][tid] + gp[1][tid] + b2[tid];
}

// ---------------------------------------------------------------------------
// 3) MFMA GEMM. bf16 in / fp32 accum (v_mfma_f32_16x16x32_bf16).
//    NSEG: K segments (1 = proj, 3 = fusion hf|hr|skip).
//    OB16: write bf16 output (attn consumer).
//    AEMB: skip-path source is virtual x = g[b]+emb[n] (computed in staging).
//    RO:   fused readout — no output write; per-block LDS-reduce
//          pred partial, exactly 2 atomicAdds per row (deterministic).
//    Block = 32 rows x 64 cols, 4 waves (2M x 2N), K chunks of 128 in LDS
//    with XOR-swizzled 16B granules.
// ---------------------------------------------------------------------------
template<int NSEG, bool OB16, bool AEMB, bool RO>
__global__ __launch_bounds__(256) void gemm_mfma(
        const float* __restrict__ a0, const float* __restrict__ a1,
        const float* __restrict__ a2,
        const float* __restrict__ gvec, const float* __restrict__ emb,
        const unsigned short* __restrict__ wba, const unsigned short* __restrict__ wbb,
        const float* __restrict__ bias1, const float* __restrict__ bias2,
        float* __restrict__ outa, float* __restrict__ outb,
        const float* __restrict__ Wro, const float* __restrict__ bro,
        float* __restrict__ pred) {
    const unsigned short* wb = blockIdx.y ? wbb : wba;
    float* out = blockIdx.y ? outb : outa;
    const int KW = NSEG * 128;   // weight row stride (ushorts)

    __shared__ __align__(16) short As[32 * 128];
    __shared__ __align__(16) short Bs[64 * 128];
    __shared__ float part[2][32];

    const int bid = blockIdx.x;
    const int ct = bid & 1, rt = bid >> 1;
    const int row0 = rt * 32, col0 = ct * 64;
    const int tid = threadIdx.x;
    const int lane = tid & 63, w = tid >> 6;
    const int wm = w >> 1, wn = w & 1;
    const int lrow = lane & 15, lk = lane >> 4;

    f32x4 acc0 = {0.f, 0.f, 0.f, 0.f};
    f32x4 acc1 = {0.f, 0.f, 0.f, 0.f};

    for (int seg = 0; seg < NSEG; ++seg) {
        const float* src = (seg == 0) ? a0 : ((seg == 1) ? a1 : a2);
        const bool useEmb = AEMB && (NSEG == 1 || seg == 2);
        if (seg) __syncthreads();
        // stage A: 32 rows x 128 k, fp32 -> bf16, swizzled 16B granules
        for (int gi = tid; gi < 512; gi += 256) {
            const int r = gi >> 4, kq = gi & 15;
            float4 v0, v1;
            if (useEmb) {
                const int row = row0 + r;
                const float4* gp = (const float4*)(gvec + (size_t)(row >> 10) * H_SZ) + kq * 2;
                const float4* ep = (const float4*)(emb + (size_t)(row & 1023) * H_SZ) + kq * 2;
                const float4 g0 = gp[0], g1 = gp[1], e0 = ep[0], e1 = ep[1];
                v0.x = g0.x + e0.x; v0.y = g0.y + e0.y; v0.z = g0.z + e0.z; v0.w = g0.w + e0.w;
                v1.x = g1.x + e1.x; v1.y = g1.y + e1.y; v1.z = g1.z + e1.z; v1.w = g1.w + e1.w;
            } else {
                const float4* sp = (const float4*)(src + (size_t)(row0 + r) * H_SZ) + kq * 2;
                v0 = sp[0]; v1 = sp[1];
            }
            u16x8 t;
            t[0] = f2bf(v0.x); t[1] = f2bf(v0.y); t[2] = f2bf(v0.z); t[3] = f2bf(v0.w);
            t[4] = f2bf(v1.x); t[5] = f2bf(v1.y); t[6] = f2bf(v1.z); t[7] = f2bf(v1.w);
            *(u16x8*)&As[r * 128 + ((kq * 8) ^ ((r & 7) << 3))] = t;
        }
        // stage B: 64 cols x 128 k (already bf16, contiguous 16B per granule)
        for (int gi = tid; gi < 1024; gi += 256) {
            const int c = gi >> 4, kq = gi & 15;
            const float4 v = *(const float4*)(wb + (size_t)(col0 + c) * KW + seg * 128 + kq * 8);
            *(float4*)&Bs[c * 128 + ((kq * 8) ^ ((c & 7) << 3))] = v;
        }
        __syncthreads();

        #pragma unroll
        for (int ks = 0; ks < 4; ++ks) {
            const int kof = ks * 32 + lk * 8;
            const int r = wm * 16 + lrow;
            const bf16x8 a = *(const bf16x8*)&As[r * 128 + (kof ^ ((r & 7) << 3))];
            const int c0 = wn * 32 + lrow;
            const bf16x8 b0 = *(const bf16x8*)&Bs[c0 * 128 + (kof ^ ((c0 & 7) << 3))];
            const int c1 = c0 + 16;
            const bf16x8 b1 = *(const bf16x8*)&Bs[c1 * 128 + (kof ^ ((c1 & 7) << 3))];
            acc0 = __builtin_amdgcn_mfma_f32_16x16x32_bf16(a, b0, acc0, 0, 0, 0);
            acc1 = __builtin_amdgcn_mfma_f32_16x16x32_bf16(a, b1, acc1, 0, 0, 0);
        }
    }

    // epilogue: D lane l reg r -> row=(l>>4)*4+r, col=l&15
    const int rb = row0 + wm * 16 + lk * 4;
    if constexpr (RO) {
        float pr[4] = {0.f, 0.f, 0.f, 0.f};
        #pragma unroll
        for (int fc = 0; fc < 2; ++fc) {
            const int c = col0 + wn * 32 + fc * 16 + lrow;
            const float bias = bias1[c] + bias2[c];
            const float wro = Wro[c];
            const f32x4 a = fc ? acc1 : acc0;
            #pragma unroll
            for (int rr = 0; rr < 4; ++rr) pr[rr] += (a[rr] + bias) * wro;
        }
        #pragma unroll
        for (int rr = 0; rr < 4; ++rr) {
            pr[rr] += __shfl_xor(pr[rr], 1);
            pr[rr] += __shfl_xor(pr[rr], 2);
            pr[rr] += __shfl_xor(pr[rr], 4);
            pr[rr] += __shfl_xor(pr[rr], 8);
        }
        if (lrow == 0) {
            #pragma unroll
            for (int rr = 0; rr < 4; ++rr) part[wn][wm * 16 + lk * 4 + rr] = pr[rr];
        }
        __syncthreads();
        if (tid < 32) {
            float v = part[0][tid] + part[1][tid];
            if (ct == 0) v += bro[0];
            atomicAdd(pred + row0 + tid, v);   // exactly 2 adds/row: deterministic
        }
    } else {
        #pragma unroll
        for (int fc = 0; fc < 2; ++fc) {
            const int c = col0 + wn * 32 + fc * 16 + lrow;
            const float bias = (bias1 ? bias1[c] : 0.0f) + (bias2 ? bias2[c] : 0.0f);
            const f32x4 a = fc ? acc1 : acc0;
            #pragma unroll
            for (int rr = 0; rr < 4; ++rr) {
                if constexpr (OB16) {
                    ((unsigned short*)out)[(size_t)(rb + rr) * H_SZ + c] = f2bf(a[rr] + bias);
                } else {
                    out[(size_t)(rb + rr) * H_SZ + c] = a[rr] + bias;
                }
            }
        }
    }
}

// ---------------------------------------------------------------------------
// 4) Sparse masked attention + ELU, bf16 coalesced neighbor-parallel.
//    (round-16 config: one load instruction covers 4 complete 256B kv rows)
// ---------------------------------------------------------------------------
__global__ __launch_bounds__(256) void attn_kernel(
        const unsigned short* __restrict__ Wha, const unsigned short* __restrict__ Whb,
        const int* __restrict__ ia, const int* __restrict__ ib,
        const int* __restrict__ da, const int* __restrict__ db,
        float* __restrict__ oa, float* __restrict__ ob) {
    const unsigned short* Wh = blockIdx.y ? Whb : Wha;
    const int* idx = blockIdx.y ? ib : ia;
    const int* deg = blockIdx.y ? db : da;
    float* out = blockIdx.y ? ob : oa;

    const int bid = blockIdx.x;
    const int b = bid & 7;                                  // batch -> XCD
    const int i = ((bid >> 3) << 2) | (threadIdx.x >> 6);   // row
    const int bi = b * N_SZ + i;
    const int lane = threadIdx.x & 63;
    const int c = lane & 15;      // 16B chunk (8 channels) within a 256B row
    const int e4 = lane >> 4;     // which of the 4 edges per instruction

    const u32x4 qb = *(const u32x4*)(Wh + (size_t)bi * H_SZ + c * 8);
    float qf[8];
    #pragma unroll
    for (int m = 0; m < 4; ++m) {
        qf[2 * m]     = __builtin_bit_cast(float, qb[m] << 16) * 0.25505654741110714f;
        qf[2 * m + 1] = __builtin_bit_cast(float, qb[m] & 0xffff0000u) * 0.25505654741110714f;
    }

    const int dg = deg[i];
    const int* row = idx + (size_t)i * CAP;
    int idxv0 = row[lane] & 1023;
    int idxv1 = (dg > 64) ? (row[64 + lane] & 1023) : 0;

    const unsigned short* kbase = Wh + (size_t)b * N_SZ * H_SZ;

    float acc[8];
    #pragma unroll
    for (int k = 0; k < 8; ++k) acc[k] = 0.0f;
    float l = 0.0f;

    const int nseg = (dg + 15) >> 4;
    for (int seg = 0; seg < nseg; ++seg) {
        const int srcv = (seg >= 4) ? idxv1 : idxv0;
        const int off16 = (seg & 3) << 4;
        u32x4 kv[4];
        #pragma unroll
        for (int t = 0; t < 4; ++t) {
            const int j0 = __builtin_amdgcn_readlane(srcv, off16 + 4 * t);
            const int j1 = __builtin_amdgcn_readlane(srcv, off16 + 4 * t + 1);
            const int j2 = __builtin_amdgcn_readlane(srcv, off16 + 4 * t + 2);
            const int j3 = __builtin_amdgcn_readlane(srcv, off16 + 4 * t + 3);
            const int jlo = (e4 & 1) ? j1 : j0;
            const int jhi = (e4 & 1) ? j3 : j2;
            const int j = (e4 & 2) ? jhi : jlo;
            kv[t] = *(const u32x4*)(kbase + (size_t)j * H_SZ + c * 8);
        }
        const int ebase = seg << 4;
        #pragma unroll
        for (int t = 0; t < 4; ++t) {
            float kf[8];
            #pragma unroll
            for (int m = 0; m < 4; ++m) {
                kf[2 * m]     = __builtin_bit_cast(float, kv[t][m] << 16);
                kf[2 * m + 1] = __builtin_bit_cast(float, kv[t][m] & 0xffff0000u);
            }
            float s = 0.0f;
            #pragma unroll
            for (int k = 0; k < 8; ++k) s += qf[k] * kf[k];
            s += __shfl_xor(s, 1);
            s += __shfl_xor(s, 2);
            const bool valid = (ebase + 4 * t + e4) < dg;
            const float p = valid ? __builtin_amdgcn_exp2f(s) : 0.0f;
            l += p;
            #pragma unroll
            for (int k = 0; k < 8; ++k) acc[k] += p * kf[k];
        }
    }

    l += __shfl_xor(l, 16);
    l += __shfl_xor(l, 32);
    #pragma unroll
    for (int k = 0; k < 8; ++k) {
        acc[k] += __shfl_xor(acc[k], 16);
        acc[k] += __shfl_xor(acc[k], 32);
    }

    if (e4 == 0) {
        const float inv = 1.0f / l;
        float o[8];
        #pragma unroll
        for (int k = 0; k < 8; ++k) {
            const float hp = acc[k] * inv;
            o[k] = (hp > 0.0f) ? hp
                 : (__builtin_amdgcn_exp2f(hp * 1.4426950408889634f) - 1.0f);
        }
        float4 v0 = {o[0], o[1], o[2], o[3]};
        float4 v1 = {o[4], o[5], o[6], o[7]};
        *(float4*)(out + (size_t)bi * H_SZ + c * 8) = v0;
        *(float4*)(out + (size_t)bi * H_SZ + c * 8 + 4) = v1;
    }
}

// ---------------------------------------------------------------------------
extern "C" void kernel_launch(void* const* d_in, const int* in_sizes, int n_in,
                              void* d_out, int out_size, void* d_ws, size_t ws_size,
                              hipStream_t stream) {
    const float* stim   = (const float*)d_in[0];
    const float* W_enc1 = (const float*)d_in[1];
    const float* b_enc1 = (const float*)d_in[2];
    const float* ln_g   = (const float*)d_in[3];
    const float* ln_b   = (const float*)d_in[4];
    const float* W_enc2 = (const float*)d_in[5];
    const float* b_enc2 = (const float*)d_in[6];
    const float* vox    = (const float*)d_in[7];
    const float* W_f1   = (const float*)d_in[8];
    const float* W_r1   = (const float*)d_in[9];
    const float* W_f2   = (const float*)d_in[10];
    const float* W_r2   = (const float*)d_in[11];
    const float* W_fu1  = (const float*)d_in[12];
    const float* b_fu1  = (const float*)d_in[13];
    const float* W_fu2  = (const float*)d_in[14];
    const float* b_fu2  = (const float*)d_in[15];
    const float* W_sk1  = (const float*)d_in[16];
    const float* b_sk1  = (const float*)d_in[17];
    const float* W_sk2  = (const float*)d_in[18];
    const float* b_sk2  = (const float*)d_in[19];
    const float* W_ro   = (const float*)d_in[20];
    const float* b_ro   = (const float*)d_in[21];
    const float* mask_f = (const float*)d_in[22];
    const float* mask_r = (const float*)d_in[23];

    float* pred = (float*)d_out;

    // workspace layout (floats)
    float* ws  = (float*)d_ws;
    float* z   = ws;                    // 8*256
    float* g   = z + 2048;              // 8*128
    float* x2  = g + 1024;              // 8*1024*128 fp32
    float* hf  = x2 + 1048576;
    float* hr  = hf + 1048576;
    unsigned short* Whf16 = (unsigned short*)(hr + 1048576);  // 1048576 ushorts
    unsigned short* Whr16 = Whf16 + 1048576;
    int* idxf  = (int*)(Whr16 + 1048576);   // 1024*CAP
    int* idxr  = idxf + N_SZ * CAP;
    int* degf  = idxr + N_SZ * CAP;
    int* degr  = degf + N_SZ;
    unsigned short* wb16 = (unsigned short*)(degr + N_SZ);   // 163840 ushorts
    unsigned short* wcat1 = wb16;
    unsigned short* wcat2 = wb16 + 49152;
    unsigned short* wpf1  = wb16 + 98304;
    unsigned short* wpr1  = wb16 + 114688;
    unsigned short* wpf2  = wb16 + 131072;
    unsigned short* wpr2  = wb16 + 147456;

    const int BN = B_SZ * N_SZ;  // 8192

    // pred accumulated via 2 deterministic atomicAdds/row — zero it (captured)
    hipMemsetAsync(pred, 0, BN * sizeof(float), stream);

    // prep: cvtw + csr + enc1 in one launch
    prep_kernel<<<896, 256, 0, stream>>>(
        W_fu1, W_sk1, W_fu2, W_sk2, W_f1, W_r1, W_f2, W_r2, wb16,
        mask_f, mask_r, idxf, idxr, degf, degr,
        stim, W_enc1, b_enc1, z);
    // LN + GELU + enc3
    enc23_kernel<<<B_SZ, 256, 0, stream>>>(z, ln_g, ln_b, W_enc2, b_enc2, g);

    // ---- GAT layer 1 (x = g+emb virtual) ----
    gemm_mfma<1, true, true, false><<<dim3(BN / 32 * 2, 2), 256, 0, stream>>>(
        nullptr, nullptr, nullptr, g, vox, wpf1, wpr1, nullptr, nullptr,
        (float*)Whf16, (float*)Whr16, nullptr, nullptr, nullptr);
    attn_kernel<<<dim3(BN / 4, 2), 256, 0, stream>>>(Whf16, Whr16, idxf, idxr, degf, degr,
                                                     hf, hr);
    gemm_mfma<3, false, true, false><<<dim3(BN / 32 * 2, 1), 256, 0, stream>>>(
        hf, hr, nullptr, g, vox, wcat1, wcat1, b_fu1, b_sk1,
        x2, x2, nullptr, nullptr, nullptr);

    // ---- GAT layer 2 ----
    gemm_mfma<1, true, false, false><<<dim3(BN / 32 * 2, 2), 256, 0, stream>>>(
        x2, nullptr, nullptr, nullptr, nullptr, wpf2, wpr2, nullptr, nullptr,
        (float*)Whf16, (float*)Whr16, nullptr, nullptr, nullptr);
    attn_kernel<<<dim3(BN / 4, 2), 256, 0, stream>>>(Whf16, Whr16, idxf, idxr, degf, degr,
                                                     hf, hr);
    gemm_mfma<3, false, false, true><<<dim3(BN / 32 * 2, 1), 256, 0, stream>>>(
        hf, hr, x2, nullptr, nullptr, wcat2, wcat2, b_fu2, b_sk2,
        nullptr, nullptr, W_ro, b_ro, pred);
}

// Round 18
// 96.762 us; speedup vs baseline: 1.1412x; 1.0409x over previous
//
#include <hip/hip_runtime.h>
#include <hip/hip_bf16.h>
#include <math.h>

// Problem constants
#define B_SZ 8
#define N_SZ 1024
#define D_IN 3072
#define H_SZ 128
#define NH 4
#define DH 32
#define TWO_H 256
#define LN_EPS 1e-5f
#define CAP 128    // max neighbors per row (binomial max deg ~80 << 128)

typedef __attribute__((ext_vector_type(8))) short bf16x8;
typedef __attribute__((ext_vector_type(8))) unsigned short u16x8;
typedef __attribute__((ext_vector_type(4))) float f32x4;
typedef __attribute__((ext_vector_type(4))) unsigned int u32x4;

// round-to-nearest-even fp32 -> bf16 bits
__device__ inline unsigned short f2bf(float f) {
    unsigned int u = __builtin_bit_cast(unsigned int, f);
    u += 0x7fffu + ((u >> 16) & 1u);
    return (unsigned short)(u >> 16);
}

// ---------------------------------------------------------------------------
// 1) prep: three independent jobs in one launch (256 thr each):
//    blocks [0,128)    : cvtw  — bf16-convert all GEMM weights
//    blocks [128,640)  : csr   — neighbor lists, 4 row-waves/block
//    blocks [640,896)  : enc1  — z[b][j] = b1[j] + stim[b,:].W1[j,:]
// ---------------------------------------------------------------------------
__global__ __launch_bounds__(256) void prep_kernel(
        const float* __restrict__ Wfu1, const float* __restrict__ Wsk1,
        const float* __restrict__ Wfu2, const float* __restrict__ Wsk2,
        const float* __restrict__ Wf1, const float* __restrict__ Wr1,
        const float* __restrict__ Wf2, const float* __restrict__ Wr2,
        unsigned short* __restrict__ wb,
        const float* __restrict__ m0, const float* __restrict__ m1,
        int* __restrict__ i0, int* __restrict__ i1,
        int* __restrict__ d0, int* __restrict__ d1,
        const float* __restrict__ stim, const float* __restrict__ W1,
        const float* __restrict__ b1, float* __restrict__ z) {
    const int bid = blockIdx.x;
    const int tid = threadIdx.x;

    if (bid < 128) {
        const int j = bid;
        wb[j * 384 + tid] = f2bf(Wfu1[j * 256 + tid]);
        wb[49152 + j * 384 + tid] = f2bf(Wfu2[j * 256 + tid]);
        if (tid < 128) {
            wb[j * 384 + 256 + tid]         = f2bf(Wsk1[j * 128 + tid]);
            wb[49152 + j * 384 + 256 + tid] = f2bf(Wsk2[j * 128 + tid]);
            wb[98304  + j * 128 + tid] = f2bf(Wf1[j * 128 + tid]);
            wb[114688 + j * 128 + tid] = f2bf(Wr1[j * 128 + tid]);
            wb[131072 + j * 128 + tid] = f2bf(Wf2[j * 128 + tid]);
            wb[147456 + j * 128 + tid] = f2bf(Wr2[j * 128 + tid]);
        }
    } else if (bid < 640) {
        const int bIdx = bid - 128;          // 0..511
        const int gsel = bIdx >> 8;          // graph
        const float* mask = gsel ? m1 : m0;
        int* idx = gsel ? i1 : i0;
        int* deg = gsel ? d1 : d0;
        const int row = (bIdx & 255) * 4 + (tid >> 6);
        const int lane = tid & 63;
        const float* mrow = mask + (size_t)row * N_SZ;
        int* irow = idx + (size_t)row * CAP;

        int base = 0;
        #pragma unroll 4
        for (int t = 0; t < N_SZ / 64; ++t) {
            int c = t * 64 + lane;
            bool edge = (mrow[c] == 0.0f);
            unsigned long long ball = __ballot(edge);
            unsigned long long below = ball & ((1ull << lane) - 1ull);
            if (edge) {
                int p = base + __popcll(below);
                if (p < CAP) irow[p] = c;
            }
            base += __popcll(ball);
        }
        if (lane == 0) deg[row] = (base < CAP) ? base : CAP;
    } else {
        const int j = bid - 640;      // 0..255
        const float4* w4 = (const float4*)(W1 + (size_t)j * D_IN);
        const float4* s4 = (const float4*)stim;

        float acc[B_SZ];
        #pragma unroll
        for (int b = 0; b < B_SZ; ++b) acc[b] = 0.0f;

        #pragma unroll
        for (int i = 0; i < D_IN / 4 / 256; ++i) {
            const int k4 = tid + i * 256;
            const float4 w = w4[k4];
            #pragma unroll
            for (int b = 0; b < B_SZ; ++b) {
                const float4 s = s4[b * (D_IN / 4) + k4];
                acc[b] += s.x * w.x + s.y * w.y + s.z * w.z + s.w * w.w;
            }
        }
        #pragma unroll
        for (int b = 0; b < B_SZ; ++b) {
            float v = acc[b];
            v += __shfl_xor(v, 1);  v += __shfl_xor(v, 2);  v += __shfl_xor(v, 4);
            v += __shfl_xor(v, 8);  v += __shfl_xor(v, 16); v += __shfl_xor(v, 32);
            acc[b] = v;
        }
        __shared__ float red[4][B_SZ];
        const int wave = tid >> 6, lane = tid & 63;
        if (lane == 0) {
            #pragma unroll
            for (int b = 0; b < B_SZ; ++b) red[wave][b] = acc[b];
        }
        __syncthreads();
        if (tid < B_SZ) {
            float v = red[0][tid] + red[1][tid] + red[2][tid] + red[3][tid];
            z[tid * TWO_H + j] = v + b1[j];
        }
    }
}

// ---------------------------------------------------------------------------
// 2) enc23: LayerNorm + exact GELU + enc3 in one kernel. grid = 8 x 256.
// ---------------------------------------------------------------------------
__global__ __launch_bounds__(256) void enc23_kernel(
        const float* __restrict__ z,
        const float* __restrict__ lng, const float* __restrict__ lnb,
        const float* __restrict__ W2, const float* __restrict__ b2,
        float* __restrict__ g) {
    __shared__ float red[TWO_H];
    __shared__ float zgs[TWO_H];
    __shared__ float gp[2][H_SZ];
    const int b = blockIdx.x;
    const int tid = threadIdx.x;

    float zi = z[b * TWO_H + tid];
    red[tid] = zi; __syncthreads();
    for (int s = 128; s > 0; s >>= 1) { if (tid < s) red[tid] += red[tid + s]; __syncthreads(); }
    float mu = red[0] * (1.0f / TWO_H);
    __syncthreads();
    float dz = zi - mu;
    red[tid] = dz * dz; __syncthreads();
    for (int s = 128; s > 0; s >>= 1) { if (tid < s) red[tid] += red[tid + s]; __syncthreads(); }
    float var = red[0] * (1.0f / TWO_H);

    float zn = dz * (1.0f / sqrtf(var + LN_EPS)) * lng[tid] + lnb[tid];
    zgs[tid] = 0.5f * zn * (1.0f + erff(zn * 0.70710678118654752f));
    __syncthreads();

    const int j = tid & 127, half = tid >> 7;
    const float* w2r = W2 + (size_t)j * TWO_H + half * 128;
    const float* zh = &zgs[half * 128];
    float s = 0.0f;
    #pragma unroll 4
    for (int k = 0; k < 128; ++k) s += zh[k] * w2r[k];
    gp[half][j] = s;
    __syncthreads();
    if (tid < H_SZ) g[b * H_SZ + tid] = gp[0][tid] + gp[1][tid] + b2[tid];
}

// ---------------------------------------------------------------------------
// 3) MFMA GEMM. bf16 in / fp32 accum. NSEG segments; OB16 bf16 output;
//    AEMB: virtual x=g+emb staging (NSEG==1 or seg==2); AB16: non-emb A
//    segments are bf16 in memory (direct copy staging); RO: fused readout.
// ---------------------------------------------------------------------------
template<int NSEG, bool OB16, bool AEMB, bool RO, bool AB16>
__global__ __launch_bounds__(256) void gemm_mfma(
        const void* __restrict__ a0, const void* __restrict__ a1,
        const void* __restrict__ a2,
        const float* __restrict__ gvec, const float* __restrict__ emb,
        const unsigned short* __restrict__ wba, const unsigned short* __restrict__ wbb,
        const float* __restrict__ bias1, const float* __restrict__ bias2,
        void* __restrict__ outa, void* __restrict__ outb,
        const float* __restrict__ Wro, const float* __restrict__ bro,
        float* __restrict__ pred) {
    const unsigned short* wb = blockIdx.y ? wbb : wba;
    void* out = blockIdx.y ? outb : outa;
    const int KW = NSEG * 128;   // weight row stride (ushorts)

    __shared__ __align__(16) short As[32 * 128];
    __shared__ __align__(16) short Bs[64 * 128];
    __shared__ float part[2][32];

    const int bid = blockIdx.x;
    const int ct = bid & 1, rt = bid >> 1;
    const int row0 = rt * 32, col0 = ct * 64;
    const int tid = threadIdx.x;
    const int lane = tid & 63, w = tid >> 6;
    const int wm = w >> 1, wn = w & 1;
    const int lrow = lane & 15, lk = lane >> 4;

    f32x4 acc0 = {0.f, 0.f, 0.f, 0.f};
    f32x4 acc1 = {0.f, 0.f, 0.f, 0.f};

    for (int seg = 0; seg < NSEG; ++seg) {
        const void* src = (seg == 0) ? a0 : ((seg == 1) ? a1 : a2);
        const bool useEmb = AEMB && (NSEG == 1 || seg == 2);
        if (seg) __syncthreads();
        // stage A: 32 rows x 128 k -> bf16, swizzled 16B granules
        for (int gi = tid; gi < 512; gi += 256) {
            const int r = gi >> 4, kq = gi & 15;
            u16x8 t;
            if (useEmb) {
                const int row = row0 + r;
                const float4* gp = (const float4*)(gvec + (size_t)(row >> 10) * H_SZ) + kq * 2;
                const float4* ep = (const float4*)(emb + (size_t)(row & 1023) * H_SZ) + kq * 2;
                const float4 g0 = gp[0], g1 = gp[1], e0 = ep[0], e1 = ep[1];
                t[0] = f2bf(g0.x + e0.x); t[1] = f2bf(g0.y + e0.y);
                t[2] = f2bf(g0.z + e0.z); t[3] = f2bf(g0.w + e0.w);
                t[4] = f2bf(g1.x + e1.x); t[5] = f2bf(g1.y + e1.y);
                t[6] = f2bf(g1.z + e1.z); t[7] = f2bf(g1.w + e1.w);
            } else if (AB16) {
                t = *(const u16x8*)((const unsigned short*)src
                                    + (size_t)(row0 + r) * H_SZ + kq * 8);
            } else {
                const float4* sp = (const float4*)((const float*)src
                                    + (size_t)(row0 + r) * H_SZ) + kq * 2;
                const float4 v0 = sp[0], v1 = sp[1];
                t[0] = f2bf(v0.x); t[1] = f2bf(v0.y); t[2] = f2bf(v0.z); t[3] = f2bf(v0.w);
                t[4] = f2bf(v1.x); t[5] = f2bf(v1.y); t[6] = f2bf(v1.z); t[7] = f2bf(v1.w);
            }
            *(u16x8*)&As[r * 128 + ((kq * 8) ^ ((r & 7) << 3))] = t;
        }
        // stage B: 64 cols x 128 k (bf16, contiguous 16B per granule)
        for (int gi = tid; gi < 1024; gi += 256) {
            const int c = gi >> 4, kq = gi & 15;
            const float4 v = *(const float4*)(wb + (size_t)(col0 + c) * KW + seg * 128 + kq * 8);
            *(float4*)&Bs[c * 128 + ((kq * 8) ^ ((c & 7) << 3))] = v;
        }
        __syncthreads();

        #pragma unroll
        for (int ks = 0; ks < 4; ++ks) {
            const int kof = ks * 32 + lk * 8;
            const int r = wm * 16 + lrow;
            const bf16x8 a = *(const bf16x8*)&As[r * 128 + (kof ^ ((r & 7) << 3))];
            const int c0 = wn * 32 + lrow;
            const bf16x8 b0 = *(const bf16x8*)&Bs[c0 * 128 + (kof ^ ((c0 & 7) << 3))];
            const int c1 = c0 + 16;
            const bf16x8 b1 = *(const bf16x8*)&Bs[c1 * 128 + (kof ^ ((c1 & 7) << 3))];
            acc0 = __builtin_amdgcn_mfma_f32_16x16x32_bf16(a, b0, acc0, 0, 0, 0);
            acc1 = __builtin_amdgcn_mfma_f32_16x16x32_bf16(a, b1, acc1, 0, 0, 0);
        }
    }

    // epilogue: D lane l reg r -> row=(l>>4)*4+r, col=l&15
    const int rb = row0 + wm * 16 + lk * 4;
    if constexpr (RO) {
        float pr[4] = {0.f, 0.f, 0.f, 0.f};
        #pragma unroll
        for (int fc = 0; fc < 2; ++fc) {
            const int c = col0 + wn * 32 + fc * 16 + lrow;
            const float bias = bias1[c] + bias2[c];
            const float wro = Wro[c];
            const f32x4 a = fc ? acc1 : acc0;
            #pragma unroll
            for (int rr = 0; rr < 4; ++rr) pr[rr] += (a[rr] + bias) * wro;
        }
        #pragma unroll
        for (int rr = 0; rr < 4; ++rr) {
            pr[rr] += __shfl_xor(pr[rr], 1);
            pr[rr] += __shfl_xor(pr[rr], 2);
            pr[rr] += __shfl_xor(pr[rr], 4);
            pr[rr] += __shfl_xor(pr[rr], 8);
        }
        if (lrow == 0) {
            #pragma unroll
            for (int rr = 0; rr < 4; ++rr) part[wn][wm * 16 + lk * 4 + rr] = pr[rr];
        }
        __syncthreads();
        if (tid < 32) {
            float v = part[0][tid] + part[1][tid];
            if (ct == 0) v += bro[0];
            atomicAdd(pred + row0 + tid, v);   // exactly 2 adds/row: deterministic
        }
    } else {
        #pragma unroll
        for (int fc = 0; fc < 2; ++fc) {
            const int c = col0 + wn * 32 + fc * 16 + lrow;
            const float bias = (bias1 ? bias1[c] : 0.0f) + (bias2 ? bias2[c] : 0.0f);
            const f32x4 a = fc ? acc1 : acc0;
            #pragma unroll
            for (int rr = 0; rr < 4; ++rr) {
                if constexpr (OB16) {
                    ((unsigned short*)out)[(size_t)(rb + rr) * H_SZ + c] = f2bf(a[rr] + bias);
                } else {
                    ((float*)out)[(size_t)(rb + rr) * H_SZ + c] = a[rr] + bias;
                }
            }
        }
    }
}

// ---------------------------------------------------------------------------
// 4) Sparse masked attention + ELU, bf16, coalesced neighbor-parallel with
//    DOUBLE-BUFFERED segment prefetch (issue seg s+1's 4 gathers before
//    computing seg s — named kvA/kvB buffers, all indexing compile-time).
//    Output written directly as bf16 (bit-identical to fp32-write + consumer
//    conversion, since all consumers convert to bf16 anyway).
// ---------------------------------------------------------------------------
__global__ __launch_bounds__(256) void attn_kernel(
        const unsigned short* __restrict__ Wha, const unsigned short* __restrict__ Whb,
        const int* __restrict__ ia, const int* __restrict__ ib,
        const int* __restrict__ da, const int* __restrict__ db,
        unsigned short* __restrict__ oa, unsigned short* __restrict__ ob) {
    const unsigned short* Wh = blockIdx.y ? Whb : Wha;
    const int* idx = blockIdx.y ? ib : ia;
    const int* deg = blockIdx.y ? db : da;
    unsigned short* out = blockIdx.y ? ob : oa;

    const int bid = blockIdx.x;
    const int b = bid & 7;                                  // batch -> XCD
    const int i = ((bid >> 3) << 2) | (threadIdx.x >> 6);   // row
    const int bi = b * N_SZ + i;
    const int lane = threadIdx.x & 63;
    const int c = lane & 15;      // 16B chunk (8 channels) within a 256B row
    const int e4 = lane >> 4;     // which of the 4 edges per instruction

    const u32x4 qb = *(const u32x4*)(Wh + (size_t)bi * H_SZ + c * 8);
    float qf[8];
    #pragma unroll
    for (int m = 0; m < 4; ++m) {
        qf[2 * m]     = __builtin_bit_cast(float, qb[m] << 16) * 0.25505654741110714f;
        qf[2 * m + 1] = __builtin_bit_cast(float, qb[m] & 0xffff0000u) * 0.25505654741110714f;
    }

    const int dg = deg[i];
    const int* row = idx + (size_t)i * CAP;
    int idxv0 = row[lane] & 1023;
    int idxv1 = (dg > 64) ? (row[64 + lane] & 1023) : 0;

    const unsigned short* kbase = Wh + (size_t)b * N_SZ * H_SZ;

    float acc[8];
    #pragma unroll
    for (int k = 0; k < 8; ++k) acc[k] = 0.0f;
    float l = 0.0f;

    auto loadSeg = [&](int s, u32x4* kv) {
        const int srcv = (s >= 4) ? idxv1 : idxv0;
        const int off16 = (s & 3) << 4;
        #pragma unroll
        for (int t = 0; t < 4; ++t) {
            const int j0 = __builtin_amdgcn_readlane(srcv, off16 + 4 * t);
            const int j1 = __builtin_amdgcn_readlane(srcv, off16 + 4 * t + 1);
            const int j2 = __builtin_amdgcn_readlane(srcv, off16 + 4 * t + 2);
            const int j3 = __builtin_amdgcn_readlane(srcv, off16 + 4 * t + 3);
            const int jlo = (e4 & 1) ? j1 : j0;
            const int jhi = (e4 & 1) ? j3 : j2;
            const int j = (e4 & 2) ? jhi : jlo;
            kv[t] = *(const u32x4*)(kbase + (size_t)j * H_SZ + c * 8);
        }
    };
    auto computeSeg = [&](int s, const u32x4* kv) {
        const int ebase = s << 4;
        #pragma unroll
        for (int t = 0; t < 4; ++t) {
            float kf[8];
            #pragma unroll
            for (int m = 0; m < 4; ++m) {
                kf[2 * m]     = __builtin_bit_cast(float, kv[t][m] << 16);
                kf[2 * m + 1] = __builtin_bit_cast(float, kv[t][m] & 0xffff0000u);
            }
            float s2 = 0.0f;
            #pragma unroll
            for (int k = 0; k < 8; ++k) s2 += qf[k] * kf[k];
            s2 += __shfl_xor(s2, 1);
            s2 += __shfl_xor(s2, 2);
            const bool valid = (ebase + 4 * t + e4) < dg;
            const float p = valid ? __builtin_amdgcn_exp2f(s2) : 0.0f;
            l += p;
            #pragma unroll
            for (int k = 0; k < 8; ++k) acc[k] += p * kf[k];
        }
    };

    const int nseg = (dg + 15) >> 4;
    u32x4 kvA[4], kvB[4];
    loadSeg(0, kvA);
    int seg = 0;
    while (true) {
        if (seg + 1 < nseg) loadSeg(seg + 1, kvB);
        computeSeg(seg, kvA);
        ++seg; if (seg >= nseg) break;
        if (seg + 1 < nseg) loadSeg(seg + 1, kvA);
        computeSeg(seg, kvB);
        ++seg; if (seg >= nseg) break;
    }

    l += __shfl_xor(l, 16);
    l += __shfl_xor(l, 32);
    #pragma unroll
    for (int k = 0; k < 8; ++k) {
        acc[k] += __shfl_xor(acc[k], 16);
        acc[k] += __shfl_xor(acc[k], 32);
    }

    if (e4 == 0) {
        const float inv = 1.0f / l;
        u16x8 ov;
        #pragma unroll
        for (int k = 0; k < 8; ++k) {
            const float hp = acc[k] * inv;
            const float o = (hp > 0.0f) ? hp
                 : (__builtin_amdgcn_exp2f(hp * 1.4426950408889634f) - 1.0f);
            ov[k] = f2bf(o);
        }
        *(u16x8*)(out + (size_t)bi * H_SZ + c * 8) = ov;   // 16 lanes: 256B row
    }
}

// ---------------------------------------------------------------------------
extern "C" void kernel_launch(void* const* d_in, const int* in_sizes, int n_in,
                              void* d_out, int out_size, void* d_ws, size_t ws_size,
                              hipStream_t stream) {
    const float* stim   = (const float*)d_in[0];
    const float* W_enc1 = (const float*)d_in[1];
    const float* b_enc1 = (const float*)d_in[2];
    const float* ln_g   = (const float*)d_in[3];
    const float* ln_b   = (const float*)d_in[4];
    const float* W_enc2 = (const float*)d_in[5];
    const float* b_enc2 = (const float*)d_in[6];
    const float* vox    = (const float*)d_in[7];
    const float* W_f1   = (const float*)d_in[8];
    const float* W_r1   = (const float*)d_in[9];
    const float* W_f2   = (const float*)d_in[10];
    const float* W_r2   = (const float*)d_in[11];
    const float* W_fu1  = (const float*)d_in[12];
    const float* b_fu1  = (const float*)d_in[13];
    const float* W_fu2  = (const float*)d_in[14];
    const float* b_fu2  = (const float*)d_in[15];
    const float* W_sk1  = (const float*)d_in[16];
    const float* b_sk1  = (const float*)d_in[17];
    const float* W_sk2  = (const float*)d_in[18];
    const float* b_sk2  = (const float*)d_in[19];
    const float* W_ro   = (const float*)d_in[20];
    const float* b_ro   = (const float*)d_in[21];
    const float* mask_f = (const float*)d_in[22];
    const float* mask_r = (const float*)d_in[23];

    float* pred = (float*)d_out;

    // workspace layout
    float* ws  = (float*)d_ws;
    float* z   = ws;                    // 8*256
    float* g   = z + 2048;              // 8*128
    unsigned short* x2_16 = (unsigned short*)(g + 1024);     // 8192*128 bf16
    unsigned short* hf16  = x2_16 + 1048576;
    unsigned short* hr16  = hf16 + 1048576;
    unsigned short* Whf16 = hr16 + 1048576;
    unsigned short* Whr16 = Whf16 + 1048576;
    int* idxf  = (int*)(Whr16 + 1048576);   // 1024*CAP
    int* idxr  = idxf + N_SZ * CAP;
    int* degf  = idxr + N_SZ * CAP;
    int* degr  = degf + N_SZ;
    unsigned short* wb16 = (unsigned short*)(degr + N_SZ);   // 163840 ushorts
    unsigned short* wcat1 = wb16;
    unsigned short* wcat2 = wb16 + 49152;
    unsigned short* wpf1  = wb16 + 98304;
    unsigned short* wpr1  = wb16 + 114688;
    unsigned short* wpf2  = wb16 + 131072;
    unsigned short* wpr2  = wb16 + 147456;

    const int BN = B_SZ * N_SZ;  // 8192

    // pred accumulated via 2 deterministic atomicAdds/row — zero it (captured)
    hipMemsetAsync(pred, 0, BN * sizeof(float), stream);

    // prep: cvtw + csr + enc1 in one launch
    prep_kernel<<<896, 256, 0, stream>>>(
        W_fu1, W_sk1, W_fu2, W_sk2, W_f1, W_r1, W_f2, W_r2, wb16,
        mask_f, mask_r, idxf, idxr, degf, degr,
        stim, W_enc1, b_enc1, z);
    // LN + GELU + enc3
    enc23_kernel<<<B_SZ, 256, 0, stream>>>(z, ln_g, ln_b, W_enc2, b_enc2, g);

    // ---- GAT layer 1 (x = g+emb virtual) ----
    gemm_mfma<1, true, true, false, false><<<dim3(BN / 32 * 2, 2), 256, 0, stream>>>(
        nullptr, nullptr, nullptr, g, vox, wpf1, wpr1, nullptr, nullptr,
        Whf16, Whr16, nullptr, nullptr, nullptr);
    attn_kernel<<<dim3(BN / 4, 2), 256, 0, stream>>>(Whf16, Whr16, idxf, idxr, degf, degr,
                                                     hf16, hr16);
    gemm_mfma<3, true, true, false, true><<<dim3(BN / 32 * 2, 1), 256, 0, stream>>>(
        hf16, hr16, nullptr, g, vox, wcat1, wcat1, b_fu1, b_sk1,
        x2_16, x2_16, nullptr, nullptr, nullptr);

    // ---- GAT layer 2 ----
    gemm_mfma<1, true, false, false, true><<<dim3(BN / 32 * 2, 2), 256, 0, stream>>>(
        x2_16, nullptr, nullptr, nullptr, nullptr, wpf2, wpr2, nullptr, nullptr,
        Whf16, Whr16, nullptr, nullptr, nullptr);
    attn_kernel<<<dim3(BN / 4, 2), 256, 0, stream>>>(Whf16, Whr16, idxf, idxr, degf, degr,
                                                     hf16, hr16);
    gemm_mfma<3, false, false, true, true><<<dim3(BN / 32 * 2, 1), 256, 0, stream>>>(
        hf16, hr16, x2_16, nullptr, nullptr, wcat2, wcat2, b_fu2, b_sk2,
        nullptr, nullptr, W_ro, b_ro, pred);
}

// Round 19
// 88.213 us; speedup vs baseline: 1.2518x; 1.0969x over previous
//
#include <hip/hip_runtime.h>
#include <hip/hip_bf16.h>
#include <math.h>

// Problem constants
#define B_SZ 8
#define N_SZ 1024
#define D_IN 3072
#define H_SZ 128
#define NH 4
#define DH 32
#define TWO_H 256
#define LN_EPS 1e-5f
#define CAP 128    // max neighbors per row (binomial max deg ~80 << 128)

typedef __attribute__((ext_vector_type(8))) short bf16x8;
typedef __attribute__((ext_vector_type(8))) unsigned short u16x8;
typedef __attribute__((ext_vector_type(4))) float f32x4;
typedef __attribute__((ext_vector_type(4))) unsigned int u32x4;

// round-to-nearest-even fp32 -> bf16 bits
__device__ inline unsigned short f2bf(float f) {
    unsigned int u = __builtin_bit_cast(unsigned int, f);
    u += 0x7fffu + ((u >> 16) & 1u);
    return (unsigned short)(u >> 16);
}

// ---------------------------------------------------------------------------
// 1) prep: three independent jobs in one launch (256 thr each):
//    blocks [0,128)    : cvtw  — bf16-convert all GEMM weights
//    blocks [128,640)  : csr   — neighbor lists, 4 row-waves/block
//    blocks [640,896)  : enc1  — z[b][j] = b1[j] + stim[b,:].W1[j,:]
// ---------------------------------------------------------------------------
__global__ __launch_bounds__(256) void prep_kernel(
        const float* __restrict__ Wfu1, const float* __restrict__ Wsk1,
        const float* __restrict__ Wfu2, const float* __restrict__ Wsk2,
        const float* __restrict__ Wf1, const float* __restrict__ Wr1,
        const float* __restrict__ Wf2, const float* __restrict__ Wr2,
        unsigned short* __restrict__ wb,
        const float* __restrict__ m0, const float* __restrict__ m1,
        int* __restrict__ i0, int* __restrict__ i1,
        int* __restrict__ d0, int* __restrict__ d1,
        const float* __restrict__ stim, const float* __restrict__ W1,
        const float* __restrict__ b1, float* __restrict__ z) {
    const int bid = blockIdx.x;
    const int tid = threadIdx.x;

    if (bid < 128) {
        const int j = bid;
        wb[j * 384 + tid] = f2bf(Wfu1[j * 256 + tid]);
        wb[49152 + j * 384 + tid] = f2bf(Wfu2[j * 256 + tid]);
        if (tid < 128) {
            wb[j * 384 + 256 + tid]         = f2bf(Wsk1[j * 128 + tid]);
            wb[49152 + j * 384 + 256 + tid] = f2bf(Wsk2[j * 128 + tid]);
            wb[98304  + j * 128 + tid] = f2bf(Wf1[j * 128 + tid]);
            wb[114688 + j * 128 + tid] = f2bf(Wr1[j * 128 + tid]);
            wb[131072 + j * 128 + tid] = f2bf(Wf2[j * 128 + tid]);
            wb[147456 + j * 128 + tid] = f2bf(Wr2[j * 128 + tid]);
        }
    } else if (bid < 640) {
        const int bIdx = bid - 128;          // 0..511
        const int gsel = bIdx >> 8;          // graph
        const float* mask = gsel ? m1 : m0;
        int* idx = gsel ? i1 : i0;
        int* deg = gsel ? d1 : d0;
        const int row = (bIdx & 255) * 4 + (tid >> 6);
        const int lane = tid & 63;
        const float* mrow = mask + (size_t)row * N_SZ;
        int* irow = idx + (size_t)row * CAP;

        int base = 0;
        #pragma unroll 4
        for (int t = 0; t < N_SZ / 64; ++t) {
            int c = t * 64 + lane;
            bool edge = (mrow[c] == 0.0f);
            unsigned long long ball = __ballot(edge);
            unsigned long long below = ball & ((1ull << lane) - 1ull);
            if (edge) {
                int p = base + __popcll(below);
                if (p < CAP) irow[p] = c;
            }
            base += __popcll(ball);
        }
        if (lane == 0) deg[row] = (base < CAP) ? base : CAP;
    } else {
        const int j = bid - 640;      // 0..255
        const float4* w4 = (const float4*)(W1 + (size_t)j * D_IN);
        const float4* s4 = (const float4*)stim;

        float acc[B_SZ];
        #pragma unroll
        for (int b = 0; b < B_SZ; ++b) acc[b] = 0.0f;

        #pragma unroll
        for (int i = 0; i < D_IN / 4 / 256; ++i) {
            const int k4 = tid + i * 256;
            const float4 w = w4[k4];
            #pragma unroll
            for (int b = 0; b < B_SZ; ++b) {
                const float4 s = s4[b * (D_IN / 4) + k4];
                acc[b] += s.x * w.x + s.y * w.y + s.z * w.z + s.w * w.w;
            }
        }
        #pragma unroll
        for (int b = 0; b < B_SZ; ++b) {
            float v = acc[b];
            v += __shfl_xor(v, 1);  v += __shfl_xor(v, 2);  v += __shfl_xor(v, 4);
            v += __shfl_xor(v, 8);  v += __shfl_xor(v, 16); v += __shfl_xor(v, 32);
            acc[b] = v;
        }
        __shared__ float red[4][B_SZ];
        const int wave = tid >> 6, lane = tid & 63;
        if (lane == 0) {
            #pragma unroll
            for (int b = 0; b < B_SZ; ++b) red[wave][b] = acc[b];
        }
        __syncthreads();
        if (tid < B_SZ) {
            float v = red[0][tid] + red[1][tid] + red[2][tid] + red[3][tid];
            z[tid * TWO_H + j] = v + b1[j];
        }
    }
}

// ---------------------------------------------------------------------------
// 2) enc23: LayerNorm + exact GELU + enc3 in one kernel. grid = 8 x 256.
// ---------------------------------------------------------------------------
__global__ __launch_bounds__(256) void enc23_kernel(
        const float* __restrict__ z,
        const float* __restrict__ lng, const float* __restrict__ lnb,
        const float* __restrict__ W2, const float* __restrict__ b2,
        float* __restrict__ g) {
    __shared__ float red[TWO_H];
    __shared__ float zgs[TWO_H];
    __shared__ float gp[2][H_SZ];
    const int b = blockIdx.x;
    const int tid = threadIdx.x;

    float zi = z[b * TWO_H + tid];
    red[tid] = zi; __syncthreads();
    for (int s = 128; s > 0; s >>= 1) { if (tid < s) red[tid] += red[tid + s]; __syncthreads(); }
    float mu = red[0] * (1.0f / TWO_H);
    __syncthreads();
    float dz = zi - mu;
    red[tid] = dz * dz; __syncthreads();
    for (int s = 128; s > 0; s >>= 1) { if (tid < s) red[tid] += red[tid + s]; __syncthreads(); }
    float var = red[0] * (1.0f / TWO_H);

    float zn = dz * (1.0f / sqrtf(var + LN_EPS)) * lng[tid] + lnb[tid];
    zgs[tid] = 0.5f * zn * (1.0f + erff(zn * 0.70710678118654752f));
    __syncthreads();

    const int j = tid & 127, half = tid >> 7;
    const float* w2r = W2 + (size_t)j * TWO_H + half * 128;
    const float* zh = &zgs[half * 128];
    float s = 0.0f;
    #pragma unroll 4
    for (int k = 0; k < 128; ++k) s += zh[k] * w2r[k];
    gp[half][j] = s;
    __syncthreads();
    if (tid < H_SZ) g[b * H_SZ + tid] = gp[0][tid] + gp[1][tid] + b2[tid];
}

// ---------------------------------------------------------------------------
// 3) MFMA GEMM (proj-1 only now). bf16 in / fp32 accum. AEMB: A = g+emb.
// ---------------------------------------------------------------------------
template<int NSEG, bool OB16, bool AEMB, bool RO, bool AB16>
__global__ __launch_bounds__(256) void gemm_mfma(
        const void* __restrict__ a0, const void* __restrict__ a1,
        const void* __restrict__ a2,
        const float* __restrict__ gvec, const float* __restrict__ emb,
        const unsigned short* __restrict__ wba, const unsigned short* __restrict__ wbb,
        const float* __restrict__ bias1, const float* __restrict__ bias2,
        void* __restrict__ outa, void* __restrict__ outb,
        const float* __restrict__ Wro, const float* __restrict__ bro,
        float* __restrict__ pred) {
    const unsigned short* wb = blockIdx.y ? wbb : wba;
    void* out = blockIdx.y ? outb : outa;
    const int KW = NSEG * 128;   // weight row stride (ushorts)

    __shared__ __align__(16) short As[32 * 128];
    __shared__ __align__(16) short Bs[64 * 128];
    __shared__ float part[2][32];

    const int bid = blockIdx.x;
    const int ct = bid & 1, rt = bid >> 1;
    const int row0 = rt * 32, col0 = ct * 64;
    const int tid = threadIdx.x;
    const int lane = tid & 63, w = tid >> 6;
    const int wm = w >> 1, wn = w & 1;
    const int lrow = lane & 15, lk = lane >> 4;

    f32x4 acc0 = {0.f, 0.f, 0.f, 0.f};
    f32x4 acc1 = {0.f, 0.f, 0.f, 0.f};

    for (int seg = 0; seg < NSEG; ++seg) {
        const void* src = (seg == 0) ? a0 : ((seg == 1) ? a1 : a2);
        const bool useEmb = AEMB && (NSEG == 1 || seg == 2);
        if (seg) __syncthreads();
        for (int gi = tid; gi < 512; gi += 256) {
            const int r = gi >> 4, kq = gi & 15;
            u16x8 t;
            if (useEmb) {
                const int row = row0 + r;
                const float4* gp = (const float4*)(gvec + (size_t)(row >> 10) * H_SZ) + kq * 2;
                const float4* ep = (const float4*)(emb + (size_t)(row & 1023) * H_SZ) + kq * 2;
                const float4 g0 = gp[0], g1 = gp[1], e0 = ep[0], e1 = ep[1];
                t[0] = f2bf(g0.x + e0.x); t[1] = f2bf(g0.y + e0.y);
                t[2] = f2bf(g0.z + e0.z); t[3] = f2bf(g0.w + e0.w);
                t[4] = f2bf(g1.x + e1.x); t[5] = f2bf(g1.y + e1.y);
                t[6] = f2bf(g1.z + e1.z); t[7] = f2bf(g1.w + e1.w);
            } else if (AB16) {
                t = *(const u16x8*)((const unsigned short*)src
                                    + (size_t)(row0 + r) * H_SZ + kq * 8);
            } else {
                const float4* sp = (const float4*)((const float*)src
                                    + (size_t)(row0 + r) * H_SZ) + kq * 2;
                const float4 v0 = sp[0], v1 = sp[1];
                t[0] = f2bf(v0.x); t[1] = f2bf(v0.y); t[2] = f2bf(v0.z); t[3] = f2bf(v0.w);
                t[4] = f2bf(v1.x); t[5] = f2bf(v1.y); t[6] = f2bf(v1.z); t[7] = f2bf(v1.w);
            }
            *(u16x8*)&As[r * 128 + ((kq * 8) ^ ((r & 7) << 3))] = t;
        }
        for (int gi = tid; gi < 1024; gi += 256) {
            const int c = gi >> 4, kq = gi & 15;
            const float4 v = *(const float4*)(wb + (size_t)(col0 + c) * KW + seg * 128 + kq * 8);
            *(float4*)&Bs[c * 128 + ((kq * 8) ^ ((c & 7) << 3))] = v;
        }
        __syncthreads();

        #pragma unroll
        for (int ks = 0; ks < 4; ++ks) {
            const int kof = ks * 32 + lk * 8;
            const int r = wm * 16 + lrow;
            const bf16x8 a = *(const bf16x8*)&As[r * 128 + (kof ^ ((r & 7) << 3))];
            const int c0 = wn * 32 + lrow;
            const bf16x8 b0 = *(const bf16x8*)&Bs[c0 * 128 + (kof ^ ((c0 & 7) << 3))];
            const int c1 = c0 + 16;
            const bf16x8 b1 = *(const bf16x8*)&Bs[c1 * 128 + (kof ^ ((c1 & 7) << 3))];
            acc0 = __builtin_amdgcn_mfma_f32_16x16x32_bf16(a, b0, acc0, 0, 0, 0);
            acc1 = __builtin_amdgcn_mfma_f32_16x16x32_bf16(a, b1, acc1, 0, 0, 0);
        }
    }

    const int rb = row0 + wm * 16 + lk * 4;
    if constexpr (RO) {
        float pr[4] = {0.f, 0.f, 0.f, 0.f};
        #pragma unroll
        for (int fc = 0; fc < 2; ++fc) {
            const int c = col0 + wn * 32 + fc * 16 + lrow;
            const float bias = bias1[c] + bias2[c];
            const float wro = Wro[c];
            const f32x4 a = fc ? acc1 : acc0;
            #pragma unroll
            for (int rr = 0; rr < 4; ++rr) pr[rr] += (a[rr] + bias) * wro;
        }
        #pragma unroll
        for (int rr = 0; rr < 4; ++rr) {
            pr[rr] += __shfl_xor(pr[rr], 1);
            pr[rr] += __shfl_xor(pr[rr], 2);
            pr[rr] += __shfl_xor(pr[rr], 4);
            pr[rr] += __shfl_xor(pr[rr], 8);
        }
        if (lrow == 0) {
            #pragma unroll
            for (int rr = 0; rr < 4; ++rr) part[wn][wm * 16 + lk * 4 + rr] = pr[rr];
        }
        __syncthreads();
        if (tid < 32) {
            float v = part[0][tid] + part[1][tid];
            if (ct == 0) v += bro[0];
            atomicAdd(pred + row0 + tid, v);
        }
    } else {
        #pragma unroll
        for (int fc = 0; fc < 2; ++fc) {
            const int c = col0 + wn * 32 + fc * 16 + lrow;
            const float bias = (bias1 ? bias1[c] : 0.0f) + (bias2 ? bias2[c] : 0.0f);
            const f32x4 a = fc ? acc1 : acc0;
            #pragma unroll
            for (int rr = 0; rr < 4; ++rr) {
                if constexpr (OB16) {
                    ((unsigned short*)out)[(size_t)(rb + rr) * H_SZ + c] = f2bf(a[rr] + bias);
                } else {
                    ((float*)out)[(size_t)(rb + rr) * H_SZ + c] = a[rr] + bias;
                }
            }
        }
    }
}

// ---------------------------------------------------------------------------
// 4) fusproj: layer-1 fusion (3 segs) + layer-2 projections (2 graphs) in
//    ONE kernel. Block = 16 rows x 128 cols, 512 blocks, 4 waves (wave = col
//    quarter, all waves share the 16-row A fragment). After fusion, x2 tile
//    is written bf16 to global AND restaged (swizzled) into As for the two
//    projection GEMMs — no x2 re-read, one dispatch fewer. Bit-identical to
//    the separate kernels (same values, same MFMA k-order).
// ---------------------------------------------------------------------------
__global__ __launch_bounds__(256) void fusproj_kernel(
        const unsigned short* __restrict__ hf, const unsigned short* __restrict__ hr,
        const float* __restrict__ gvec, const float* __restrict__ emb,
        const unsigned short* __restrict__ wcat,
        const float* __restrict__ bfu, const float* __restrict__ bsk,
        const unsigned short* __restrict__ wpf, const unsigned short* __restrict__ wpr,
        unsigned short* __restrict__ x2, unsigned short* __restrict__ whf,
        unsigned short* __restrict__ whr) {
    __shared__ __align__(16) short As[16 * 128];
    __shared__ __align__(16) short Bs[128 * 128];
    const int row0 = blockIdx.x * 16;
    const int tid = threadIdx.x;
    const int lane = tid & 63, w = tid >> 6;   // wave = col quarter
    const int lrow = lane & 15, lk = lane >> 4;

    f32x4 acc0 = {0.f, 0.f, 0.f, 0.f};
    f32x4 acc1 = {0.f, 0.f, 0.f, 0.f};

    for (int seg = 0; seg < 3; ++seg) {
        if (seg) __syncthreads();
        {   // stage A: 16 rows x 16 granules = 256 (one per thread)
            const int r = tid >> 4, kq = tid & 15;
            u16x8 t;
            if (seg == 0) {
                t = *(const u16x8*)(hf + (size_t)(row0 + r) * H_SZ + kq * 8);
            } else if (seg == 1) {
                t = *(const u16x8*)(hr + (size_t)(row0 + r) * H_SZ + kq * 8);
            } else {
                const int row = row0 + r;
                const float4* gp = (const float4*)(gvec + (size_t)(row >> 10) * H_SZ) + kq * 2;
                const float4* ep = (const float4*)(emb + (size_t)(row & 1023) * H_SZ) + kq * 2;
                const float4 g0 = gp[0], g1 = gp[1], e0 = ep[0], e1 = ep[1];
                t[0] = f2bf(g0.x + e0.x); t[1] = f2bf(g0.y + e0.y);
                t[2] = f2bf(g0.z + e0.z); t[3] = f2bf(g0.w + e0.w);
                t[4] = f2bf(g1.x + e1.x); t[5] = f2bf(g1.y + e1.y);
                t[6] = f2bf(g1.z + e1.z); t[7] = f2bf(g1.w + e1.w);
            }
            *(u16x8*)&As[r * 128 + ((kq * 8) ^ ((r & 7) << 3))] = t;
        }
        for (int gi = tid; gi < 2048; gi += 256) {   // stage B: 128 cols
            const int c = gi >> 4, kq = gi & 15;
            const float4 v = *(const float4*)(wcat + (size_t)c * 384 + seg * 128 + kq * 8);
            *(float4*)&Bs[c * 128 + ((kq * 8) ^ ((c & 7) << 3))] = v;
        }
        __syncthreads();

        #pragma unroll
        for (int ks = 0; ks < 4; ++ks) {
            const int kof = ks * 32 + lk * 8;
            const bf16x8 a = *(const bf16x8*)&As[lrow * 128 + (kof ^ ((lrow & 7) << 3))];
            const int c0 = w * 32 + lrow;
            const bf16x8 b0 = *(const bf16x8*)&Bs[c0 * 128 + (kof ^ ((c0 & 7) << 3))];
            const int c1 = c0 + 16;
            const bf16x8 b1 = *(const bf16x8*)&Bs[c1 * 128 + (kof ^ ((c1 & 7) << 3))];
            acc0 = __builtin_amdgcn_mfma_f32_16x16x32_bf16(a, b0, acc0, 0, 0, 0);
            acc1 = __builtin_amdgcn_mfma_f32_16x16x32_bf16(a, b1, acc1, 0, 0, 0);
        }
    }
    __syncthreads();

    // epilogue: x2 = acc + bias -> global (bf16) + LDS As (swizzled)
    const int rb = lk * 4;
    #pragma unroll
    for (int fc = 0; fc < 2; ++fc) {
        const int c = w * 32 + fc * 16 + lrow;
        const float bias = bfu[c] + bsk[c];
        const f32x4 a = fc ? acc1 : acc0;
        #pragma unroll
        for (int rr = 0; rr < 4; ++rr) {
            const unsigned short v = f2bf(a[rr] + bias);
            x2[(size_t)(row0 + rb + rr) * H_SZ + c] = v;
            const int rl = rb + rr;
            As[rl * 128 + (((c & ~7) ^ ((rl & 7) << 3)) | (c & 7))] = (short)v;
        }
    }
    __syncthreads();

    // phase 2: projections for both graphs from the LDS x2 tile
    #pragma unroll
    for (int gsel = 0; gsel < 2; ++gsel) {
        const unsigned short* wp = gsel ? wpr : wpf;
        unsigned short* out = gsel ? whr : whf;
        if (gsel) __syncthreads();
        for (int gi = tid; gi < 2048; gi += 256) {
            const int c = gi >> 4, kq = gi & 15;
            const float4 v = *(const float4*)(wp + (size_t)c * 128 + kq * 8);
            *(float4*)&Bs[c * 128 + ((kq * 8) ^ ((c & 7) << 3))] = v;
        }
        __syncthreads();
        f32x4 p0 = {0.f, 0.f, 0.f, 0.f};
        f32x4 p1 = {0.f, 0.f, 0.f, 0.f};
        #pragma unroll
        for (int ks = 0; ks < 4; ++ks) {
            const int kof = ks * 32 + lk * 8;
            const bf16x8 a = *(const bf16x8*)&As[lrow * 128 + (kof ^ ((lrow & 7) << 3))];
            const int c0 = w * 32 + lrow;
            const bf16x8 b0 = *(const bf16x8*)&Bs[c0 * 128 + (kof ^ ((c0 & 7) << 3))];
            const int c1 = c0 + 16;
            const bf16x8 b1 = *(const bf16x8*)&Bs[c1 * 128 + (kof ^ ((c1 & 7) << 3))];
            p0 = __builtin_amdgcn_mfma_f32_16x16x32_bf16(a, b0, p0, 0, 0, 0);
            p1 = __builtin_amdgcn_mfma_f32_16x16x32_bf16(a, b1, p1, 0, 0, 0);
        }
        #pragma unroll
        for (int fc = 0; fc < 2; ++fc) {
            const int c = w * 32 + fc * 16 + lrow;
            const f32x4 a = fc ? p1 : p0;
            #pragma unroll
            for (int rr = 0; rr < 4; ++rr)
                out[(size_t)(row0 + rb + rr) * H_SZ + c] = f2bf(a[rr]);
        }
    }
}

// ---------------------------------------------------------------------------
// 5) fusro: layer-2 fusion (3 segs) + readout, full-width block so pred is
//    written by a SINGLE block — no atomics, no memset. 512 blocks x 256 thr.
// ---------------------------------------------------------------------------
__global__ __launch_bounds__(256) void fusro_kernel(
        const unsigned short* __restrict__ hf, const unsigned short* __restrict__ hr,
        const unsigned short* __restrict__ x2,
        const unsigned short* __restrict__ wcat,
        const float* __restrict__ bfu, const float* __restrict__ bsk,
        const float* __restrict__ Wro, const float* __restrict__ bro,
        float* __restrict__ pred) {
    __shared__ __align__(16) short As[16 * 128];
    __shared__ __align__(16) short Bs[128 * 128];
    __shared__ float part[4][16];
    const int row0 = blockIdx.x * 16;
    const int tid = threadIdx.x;
    const int lane = tid & 63, w = tid >> 6;
    const int lrow = lane & 15, lk = lane >> 4;

    f32x4 acc0 = {0.f, 0.f, 0.f, 0.f};
    f32x4 acc1 = {0.f, 0.f, 0.f, 0.f};

    for (int seg = 0; seg < 3; ++seg) {
        if (seg) __syncthreads();
        {
            const int r = tid >> 4, kq = tid & 15;
            const unsigned short* src = (seg == 0) ? hf : ((seg == 1) ? hr : x2);
            const u16x8 t = *(const u16x8*)(src + (size_t)(row0 + r) * H_SZ + kq * 8);
            *(u16x8*)&As[r * 128 + ((kq * 8) ^ ((r & 7) << 3))] = t;
        }
        for (int gi = tid; gi < 2048; gi += 256) {
            const int c = gi >> 4, kq = gi & 15;
            const float4 v = *(const float4*)(wcat + (size_t)c * 384 + seg * 128 + kq * 8);
            *(float4*)&Bs[c * 128 + ((kq * 8) ^ ((c & 7) << 3))] = v;
        }
        __syncthreads();

        #pragma unroll
        for (int ks = 0; ks < 4; ++ks) {
            const int kof = ks * 32 + lk * 8;
            const bf16x8 a = *(const bf16x8*)&As[lrow * 128 + (kof ^ ((lrow & 7) << 3))];
            const int c0 = w * 32 + lrow;
            const bf16x8 b0 = *(const bf16x8*)&Bs[c0 * 128 + (kof ^ ((c0 & 7) << 3))];
            const int c1 = c0 + 16;
            const bf16x8 b1 = *(const bf16x8*)&Bs[c1 * 128 + (kof ^ ((c1 & 7) << 3))];
            acc0 = __builtin_amdgcn_mfma_f32_16x16x32_bf16(a, b0, acc0, 0, 0, 0);
            acc1 = __builtin_amdgcn_mfma_f32_16x16x32_bf16(a, b1, acc1, 0, 0, 0);
        }
    }

    // readout: pred[row] = sum_c (v[row][c]) * Wro[c] + bro
    const int rb = lk * 4;
    float pr[4] = {0.f, 0.f, 0.f, 0.f};
    #pragma unroll
    for (int fc = 0; fc < 2; ++fc) {
        const int c = w * 32 + fc * 16 + lrow;
        const float bias = bfu[c] + bsk[c];
        const float wro = Wro[c];
        const f32x4 a = fc ? acc1 : acc0;
        #pragma unroll
        for (int rr = 0; rr < 4; ++rr) pr[rr] += (a[rr] + bias) * wro;
    }
    #pragma unroll
    for (int rr = 0; rr < 4; ++rr) {
        pr[rr] += __shfl_xor(pr[rr], 1);
        pr[rr] += __shfl_xor(pr[rr], 2);
        pr[rr] += __shfl_xor(pr[rr], 4);
        pr[rr] += __shfl_xor(pr[rr], 8);
    }
    if (lrow == 0) {
        #pragma unroll
        for (int rr = 0; rr < 4; ++rr) part[w][rb + rr] = pr[rr];
    }
    __syncthreads();
    if (tid < 16)
        pred[row0 + tid] = part[0][tid] + part[1][tid] + part[2][tid] + part[3][tid] + bro[0];
}

// ---------------------------------------------------------------------------
// 6) Sparse masked attention + ELU, bf16, coalesced neighbor-parallel with
//    double-buffered segment prefetch. (round-18 proven config)
// ---------------------------------------------------------------------------
__global__ __launch_bounds__(256) void attn_kernel(
        const unsigned short* __restrict__ Wha, const unsigned short* __restrict__ Whb,
        const int* __restrict__ ia, const int* __restrict__ ib,
        const int* __restrict__ da, const int* __restrict__ db,
        unsigned short* __restrict__ oa, unsigned short* __restrict__ ob) {
    const unsigned short* Wh = blockIdx.y ? Whb : Wha;
    const int* idx = blockIdx.y ? ib : ia;
    const int* deg = blockIdx.y ? db : da;
    unsigned short* out = blockIdx.y ? ob : oa;

    const int bid = blockIdx.x;
    const int b = bid & 7;                                  // batch -> XCD
    const int i = ((bid >> 3) << 2) | (threadIdx.x >> 6);   // row
    const int bi = b * N_SZ + i;
    const int lane = threadIdx.x & 63;
    const int c = lane & 15;
    const int e4 = lane >> 4;

    const u32x4 qb = *(const u32x4*)(Wh + (size_t)bi * H_SZ + c * 8);
    float qf[8];
    #pragma unroll
    for (int m = 0; m < 4; ++m) {
        qf[2 * m]     = __builtin_bit_cast(float, qb[m] << 16) * 0.25505654741110714f;
        qf[2 * m + 1] = __builtin_bit_cast(float, qb[m] & 0xffff0000u) * 0.25505654741110714f;
    }

    const int dg = deg[i];
    const int* row = idx + (size_t)i * CAP;
    int idxv0 = row[lane] & 1023;
    int idxv1 = (dg > 64) ? (row[64 + lane] & 1023) : 0;

    const unsigned short* kbase = Wh + (size_t)b * N_SZ * H_SZ;

    float acc[8];
    #pragma unroll
    for (int k = 0; k < 8; ++k) acc[k] = 0.0f;
    float l = 0.0f;

    auto loadSeg = [&](int s, u32x4* kv) {
        const int srcv = (s >= 4) ? idxv1 : idxv0;
        const int off16 = (s & 3) << 4;
        #pragma unroll
        for (int t = 0; t < 4; ++t) {
            const int j0 = __builtin_amdgcn_readlane(srcv, off16 + 4 * t);
            const int j1 = __builtin_amdgcn_readlane(srcv, off16 + 4 * t + 1);
            const int j2 = __builtin_amdgcn_readlane(srcv, off16 + 4 * t + 2);
            const int j3 = __builtin_amdgcn_readlane(srcv, off16 + 4 * t + 3);
            const int jlo = (e4 & 1) ? j1 : j0;
            const int jhi = (e4 & 1) ? j3 : j2;
            const int j = (e4 & 2) ? jhi : jlo;
            kv[t] = *(const u32x4*)(kbase + (size_t)j * H_SZ + c * 8);
        }
    };
    auto computeSeg = [&](int s, const u32x4* kv) {
        const int ebase = s << 4;
        #pragma unroll
        for (int t = 0; t < 4; ++t) {
            float kf[8];
            #pragma unroll
            for (int m = 0; m < 4; ++m) {
                kf[2 * m]     = __builtin_bit_cast(float, kv[t][m] << 16);
                kf[2 * m + 1] = __builtin_bit_cast(float, kv[t][m] & 0xffff0000u);
            }
            float s2 = 0.0f;
            #pragma unroll
            for (int k = 0; k < 8; ++k) s2 += qf[k] * kf[k];
            s2 += __shfl_xor(s2, 1);
            s2 += __shfl_xor(s2, 2);
            const bool valid = (ebase + 4 * t + e4) < dg;
            const float p = valid ? __builtin_amdgcn_exp2f(s2) : 0.0f;
            l += p;
            #pragma unroll
            for (int k = 0; k < 8; ++k) acc[k] += p * kf[k];
        }
    };

    const int nseg = (dg + 15) >> 4;
    u32x4 kvA[4], kvB[4];
    loadSeg(0, kvA);
    int seg = 0;
    while (true) {
        if (seg + 1 < nseg) loadSeg(seg + 1, kvB);
        computeSeg(seg, kvA);
        ++seg; if (seg >= nseg) break;
        if (seg + 1 < nseg) loadSeg(seg + 1, kvA);
        computeSeg(seg, kvB);
        ++seg; if (seg >= nseg) break;
    }

    l += __shfl_xor(l, 16);
    l += __shfl_xor(l, 32);
    #pragma unroll
    for (int k = 0; k < 8; ++k) {
        acc[k] += __shfl_xor(acc[k], 16);
        acc[k] += __shfl_xor(acc[k], 32);
    }

    if (e4 == 0) {
        const float inv = 1.0f / l;
        u16x8 ov;
        #pragma unroll
        for (int k = 0; k < 8; ++k) {
            const float hp = acc[k] * inv;
            const float o = (hp > 0.0f) ? hp
                 : (__builtin_amdgcn_exp2f(hp * 1.4426950408889634f) - 1.0f);
            ov[k] = f2bf(o);
        }
        *(u16x8*)(out + (size_t)bi * H_SZ + c * 8) = ov;
    }
}

// ---------------------------------------------------------------------------
extern "C" void kernel_launch(void* const* d_in, const int* in_sizes, int n_in,
                              void* d_out, int out_size, void* d_ws, size_t ws_size,
                              hipStream_t stream) {
    const float* stim   = (const float*)d_in[0];
    const float* W_enc1 = (const float*)d_in[1];
    const float* b_enc1 = (const float*)d_in[2];
    const float* ln_g   = (const float*)d_in[3];
    const float* ln_b   = (const float*)d_in[4];
    const float* W_enc2 = (const float*)d_in[5];
    const float* b_enc2 = (const float*)d_in[6];
    const float* vox    = (const float*)d_in[7];
    const float* W_f1   = (const float*)d_in[8];
    const float* W_r1   = (const float*)d_in[9];
    const float* W_f2   = (const float*)d_in[10];
    const float* W_r2   = (const float*)d_in[11];
    const float* W_fu1  = (const float*)d_in[12];
    const float* b_fu1  = (const float*)d_in[13];
    const float* W_fu2  = (const float*)d_in[14];
    const float* b_fu2  = (const float*)d_in[15];
    const float* W_sk1  = (const float*)d_in[16];
    const float* b_sk1  = (const float*)d_in[17];
    const float* W_sk2  = (const float*)d_in[18];
    const float* b_sk2  = (const float*)d_in[19];
    const float* W_ro   = (const float*)d_in[20];
    const float* b_ro   = (const float*)d_in[21];
    const float* mask_f = (const float*)d_in[22];
    const float* mask_r = (const float*)d_in[23];

    float* pred = (float*)d_out;

    // workspace layout
    float* ws  = (float*)d_ws;
    float* z   = ws;                    // 8*256
    float* g   = z + 2048;              // 8*128
    unsigned short* x2_16 = (unsigned short*)(g + 1024);     // 8192*128 bf16
    unsigned short* hf16  = x2_16 + 1048576;
    unsigned short* hr16  = hf16 + 1048576;
    unsigned short* Whf16 = hr16 + 1048576;
    unsigned short* Whr16 = Whf16 + 1048576;
    int* idxf  = (int*)(Whr16 + 1048576);   // 1024*CAP
    int* idxr  = idxf + N_SZ * CAP;
    int* degf  = idxr + N_SZ * CAP;
    int* degr  = degf + N_SZ;
    unsigned short* wb16 = (unsigned short*)(degr + N_SZ);   // 163840 ushorts
    unsigned short* wcat1 = wb16;
    unsigned short* wcat2 = wb16 + 49152;
    unsigned short* wpf1  = wb16 + 98304;
    unsigned short* wpr1  = wb16 + 114688;
    unsigned short* wpf2  = wb16 + 131072;
    unsigned short* wpr2  = wb16 + 147456;

    const int BN = B_SZ * N_SZ;  // 8192

    // prep: cvtw + csr + enc1 in one launch
    prep_kernel<<<896, 256, 0, stream>>>(
        W_fu1, W_sk1, W_fu2, W_sk2, W_f1, W_r1, W_f2, W_r2, wb16,
        mask_f, mask_r, idxf, idxr, degf, degr,
        stim, W_enc1, b_enc1, z);
    // LN + GELU + enc3
    enc23_kernel<<<B_SZ, 256, 0, stream>>>(z, ln_g, ln_b, W_enc2, b_enc2, g);

    // ---- GAT layer 1 (x = g+emb virtual) ----
    gemm_mfma<1, true, true, false, false><<<dim3(BN / 32 * 2, 2), 256, 0, stream>>>(
        nullptr, nullptr, nullptr, g, vox, wpf1, wpr1, nullptr, nullptr,
        Whf16, Whr16, nullptr, nullptr, nullptr);
    attn_kernel<<<dim3(BN / 4, 2), 256, 0, stream>>>(Whf16, Whr16, idxf, idxr, degf, degr,
                                                     hf16, hr16);
    // fusion-1 + proj-2 fused
    fusproj_kernel<<<BN / 16, 256, 0, stream>>>(
        hf16, hr16, g, vox, wcat1, b_fu1, b_sk1, wpf2, wpr2,
        x2_16, Whf16, Whr16);

    // ---- GAT layer 2 ----
    attn_kernel<<<dim3(BN / 4, 2), 256, 0, stream>>>(Whf16, Whr16, idxf, idxr, degf, degr,
                                                     hf16, hr16);
    // fusion-2 + readout fused (single writer per pred row)
    fusro_kernel<<<BN / 16, 256, 0, stream>>>(
        hf16, hr16, x2_16, wcat2, b_fu2, b_sk2, W_ro, b_ro, pred);
}